// Round 5
// baseline (235.962 us; speedup 1.0000x reference)
//
#include <hip/hip_runtime.h>
#include <math.h>

typedef __bf16 bf16_t;
typedef __bf16 bf16x8 __attribute__((ext_vector_type(8)));
typedef __bf16 bf16x4v __attribute__((ext_vector_type(4)));
typedef float f32x4 __attribute__((ext_vector_type(4)));
typedef float f32x16 __attribute__((ext_vector_type(16)));

#define LOG2E 1.4426950408889634f
#define MBIAS_C (-1e12f * LOG2E)

#if __has_builtin(__builtin_amdgcn_exp2f)
#define EXP2F(x) __builtin_amdgcn_exp2f(x)
#else
#define EXP2F(x) exp2f(x)
#endif

typedef __attribute__((address_space(1))) const unsigned int g_u32;
typedef __attribute__((address_space(3))) unsigned int l_u32;
__device__ __forceinline__ void load_lds_16B(const void* g, void* l){
  __builtin_amdgcn_global_load_lds((g_u32*)g, (l_u32*)l, 16, 0, 0);
}

__device__ __forceinline__ f32x16 zero16(){
  f32x16 z;
  #pragma unroll
  for (int i = 0; i < 16; i++) z[i] = 0.f;
  return z;
}

typedef union { bf16x4v b4; uint2 u2; } pk8;
typedef union { uint2 h[2]; bf16x8 b8; } pk16;
typedef union { float4 f4[4]; f32x16 v; } cinit_t;

// ---------------- cast q,k,v fp32 -> bf16 planes ----------------
__global__ __launch_bounds__(256) void cast3_kernel(const float* __restrict__ q,
                                                    const float* __restrict__ k,
                                                    const float* __restrict__ v,
                                                    bf16_t* __restrict__ out){
  int z = blockIdx.y;
  const float* x = (z == 0) ? q : (z == 1) ? k : v;
  int i = blockIdx.x * 256 + threadIdx.x;
  float4 f = reinterpret_cast<const float4*>(x)[i];
  bf16x4v w;
  w[0] = (bf16_t)f.x; w[1] = (bf16_t)f.y; w[2] = (bf16_t)f.z; w[3] = (bf16_t)f.w;
  reinterpret_cast<bf16x4v*>(out + (size_t)z * 4194304)[i] = w;
}

// ---------------- mask prescale: ms[i] = mask[i] * (-1e12 * log2e) ----------------
__global__ __launch_bounds__(256) void mask_scale_kernel(const float* __restrict__ mask,
                                                         float* __restrict__ ms){
  int i = blockIdx.x * 256 + threadIdx.x;
  ms[i] = mask[i] * MBIAS_C;
}

// ---------------- weight transpose+cast ----------------
__global__ __launch_bounds__(256) void wtrans4_kernel(const float* __restrict__ Wq,
                                                      const float* __restrict__ Wk,
                                                      const float* __restrict__ Wv,
                                                      const float* __restrict__ Wo,
                                                      bf16_t* __restrict__ Wcat,
                                                      bf16_t* __restrict__ Wot){
  __shared__ float T[32][33];
  int z = blockIdx.z;
  const float* W = (z == 0) ? Wq : (z == 1) ? Wk : (z == 2) ? Wv : Wo;
  bf16_t* dst = (z < 3) ? (Wcat + (size_t)z * 1024 * 1024) : Wot;
  int x = threadIdx.x, y = threadIdx.y;
  int k0 = blockIdx.y * 32, n0 = blockIdx.x * 32;
  #pragma unroll
  for (int i = 0; i < 4; i++) T[y + 8*i][x] = W[(size_t)(k0 + y + 8*i) * 1024 + n0 + x];
  __syncthreads();
  #pragma unroll
  for (int i = 0; i < 4; i++) dst[(size_t)(n0 + y + 8*i) * 1024 + k0 + x] = (bf16_t)T[x][y + 8*i];
}

// ---------------- shared epilogue for QKV GEMMs: write q/k/v planes ----------------
__device__ __forceinline__ void qkv_epilogue(f32x4 (&acc)[4][4], int seg, int n0g, int m0,
                                             int wm, int wn, int l16, int lq,
                                             const float* bias, bf16_t* qp, bf16_t* kp,
                                             bf16_t* vh){
  bf16_t* Cp = (seg == 0) ? qp : (seg == 1) ? kp : vh;
  float scale = (seg == 0) ? 0.125f * LOG2E : 1.0f;  // fold softmax scale + log2e into Q
  #pragma unroll
  for (int ti = 0; ti < 4; ti++){
    #pragma unroll
    for (int tj = 0; tj < 4; tj++){
      int col = (n0g + wn + tj*16 + l16) & 1023;
      float bvv = bias[col];
      #pragma unroll
      for (int r = 0; r < 4; r++){
        int row = m0 + wm + ti*16 + lq*4 + r;
        Cp[(size_t)row * 1024 + col] = (bf16_t)((acc[ti][tj][r] + bvv) * scale);
      }
    }
  }
}

// ---------------- fused QKV GEMM, all-bf16 (path A) ----------------
__global__ __launch_bounds__(256) void gemm_qkv_bf(const bf16_t* __restrict__ qkvin,
                                                   const bf16_t* __restrict__ Wcat,
                                                   const float* __restrict__ bq,
                                                   const float* __restrict__ bk,
                                                   const float* __restrict__ bv,
                                                   bf16_t* __restrict__ qp,
                                                   bf16_t* __restrict__ kp,
                                                   bf16_t* __restrict__ vh){
  const int K = 1024;
  __shared__ __align__(16) bf16_t As[128*32];
  __shared__ __align__(16) bf16_t Bs[128*32];
  int tid = threadIdx.x, wave = tid >> 6, lane = tid & 63;
  int l16 = lane & 15, lq = lane >> 4;
  int n0g = blockIdx.x * 128;
  int seg = n0g >> 10;
  const bf16_t* A   = qkvin + (size_t)seg * 4194304;
  const float* bias = (seg == 0) ? bq : (seg == 1) ? bk : bv;
  int m0 = blockIdx.y * 128;
  int wm = (wave >> 1) * 64, wn = (wave & 1) * 64;
  int cposR = lq ^ ((l16 >> 2) & 3);
  f32x4 acc[4][4] = {};
  for (int kt = 0; kt < K; kt += 32){
    __syncthreads();
    #pragma unroll
    for (int i = 0; i < 2; i++){
      int u = tid + 256*i;
      int r = u >> 2, cpos = u & 3, cg = cpos ^ ((r >> 2) & 3);
      int ldsoff = (wave*64 + 256*i) * 16;
      load_lds_16B(&A[(size_t)(m0 + r) * K + kt + cg*8], (char*)As + ldsoff);
      load_lds_16B(&Wcat[(size_t)(n0g + r) * K + kt + cg*8], (char*)Bs + ldsoff);
    }
    __syncthreads();
    bf16x8 af[4], bfr[4];
    #pragma unroll
    for (int t = 0; t < 4; t++) af[t]  = *reinterpret_cast<bf16x8*>(&As[(wm + t*16 + l16)*32 + cposR*8]);
    #pragma unroll
    for (int t = 0; t < 4; t++) bfr[t] = *reinterpret_cast<bf16x8*>(&Bs[(wn + t*16 + l16)*32 + cposR*8]);
    #pragma unroll
    for (int ti = 0; ti < 4; ti++)
      #pragma unroll
      for (int tj = 0; tj < 4; tj++)
        acc[ti][tj] = __builtin_amdgcn_mfma_f32_16x16x32_bf16(af[ti], bfr[tj], acc[ti][tj], 0, 0, 0);
  }
  qkv_epilogue(acc, seg, n0g, m0, wm, wn, l16, lq, bias, qp, kp, vh);
}

// ---------------- fused QKV GEMM, fp32-A fused-cvt (path B fallback) ----------------
__global__ __launch_bounds__(256) void gemm_qkv_f32(const float* __restrict__ qi,
                                                    const float* __restrict__ ki,
                                                    const float* __restrict__ vi,
                                                    const bf16_t* __restrict__ Wcat,
                                                    const float* __restrict__ bq,
                                                    const float* __restrict__ bk,
                                                    const float* __restrict__ bv,
                                                    bf16_t* __restrict__ qp,
                                                    bf16_t* __restrict__ kp,
                                                    bf16_t* __restrict__ vh){
  const int K = 1024;
  __shared__ __align__(16) float  Asf[128*32];
  __shared__ __align__(16) bf16_t Bs[128*32];
  int tid = threadIdx.x, wave = tid >> 6, lane = tid & 63;
  int l16 = lane & 15, lq = lane >> 4;
  int n0g = blockIdx.x * 128;
  int seg = n0g >> 10;
  const float* A    = (seg == 0) ? qi : (seg == 1) ? ki : vi;
  const float* bias = (seg == 0) ? bq : (seg == 1) ? bk : bv;
  int m0 = blockIdx.y * 128;
  int wm = (wave >> 1) * 64, wn = (wave & 1) * 64;
  int cposR = lq ^ ((l16 >> 2) & 3);
  int ca0 = (2*lq)     ^ (l16 & 7);
  int ca1 = (2*lq + 1) ^ (l16 & 7);
  f32x4 acc[4][4] = {};
  for (int kt = 0; kt < K; kt += 32){
    __syncthreads();
    #pragma unroll
    for (int i = 0; i < 4; i++){
      int u = tid + 256*i;
      int r = u >> 3, cpos = u & 7, cg = cpos ^ (r & 7);
      load_lds_16B(&A[(size_t)(m0 + r) * K + kt + cg*4], (char*)Asf + (wave*64 + 256*i)*16);
    }
    #pragma unroll
    for (int i = 0; i < 2; i++){
      int u = tid + 256*i;
      int r = u >> 2, cpos = u & 3, cg = cpos ^ ((r >> 2) & 3);
      load_lds_16B(&Wcat[(size_t)(n0g + r) * K + kt + cg*8], (char*)Bs + (wave*64 + 256*i)*16);
    }
    __syncthreads();
    bf16x8 af[4], bfr[4];
    #pragma unroll
    for (int t = 0; t < 4; t++){
      int row = wm + t*16 + l16;
      f32x4 x0 = *reinterpret_cast<f32x4*>(&Asf[row*32 + ca0*4]);
      f32x4 x1 = *reinterpret_cast<f32x4*>(&Asf[row*32 + ca1*4]);
      bf16x8 a;
      a[0] = (bf16_t)x0[0]; a[1] = (bf16_t)x0[1]; a[2] = (bf16_t)x0[2]; a[3] = (bf16_t)x0[3];
      a[4] = (bf16_t)x1[0]; a[5] = (bf16_t)x1[1]; a[6] = (bf16_t)x1[2]; a[7] = (bf16_t)x1[3];
      af[t] = a;
    }
    #pragma unroll
    for (int t = 0; t < 4; t++) bfr[t] = *reinterpret_cast<bf16x8*>(&Bs[(wn + t*16 + l16)*32 + cposR*8]);
    #pragma unroll
    for (int ti = 0; ti < 4; ti++)
      #pragma unroll
      for (int tj = 0; tj < 4; tj++)
        acc[ti][tj] = __builtin_amdgcn_mfma_f32_16x16x32_bf16(af[ti], bfr[tj], acc[ti][tj], 0, 0, 0);
  }
  qkv_epilogue(acc, seg, n0g, m0, wm, wn, l16, lq, bias, qp, kp, vh);
}

// ---------------- output GEMM: d_out = ctx @ Wot^T + bo, fp32 out ----------------
__global__ __launch_bounds__(256) void gemm_out(const bf16_t* __restrict__ A,
                                                const bf16_t* __restrict__ Bt,
                                                const float* __restrict__ bias,
                                                float* __restrict__ C){
  const int K = 1024, N = 1024;
  __shared__ __align__(16) bf16_t As[128*64];
  __shared__ __align__(16) bf16_t Bs[64*64];
  int tid = threadIdx.x, wave = tid >> 6, lane = tid & 63;
  int l16 = lane & 15, lq = lane >> 4;
  int m0 = blockIdx.y * 128, n0 = blockIdx.x * 64;
  int wm = wave * 32;
  f32x4 acc[2][4] = {};
  for (int kt = 0; kt < K; kt += 64){
    __syncthreads();
    #pragma unroll
    for (int i = 0; i < 4; i++){
      int u = tid + 256*i;
      int r = u >> 3, cpos = u & 7, cg = cpos ^ (r & 7);
      load_lds_16B(&A[(size_t)(m0 + r) * K + kt + cg*8], (char*)As + (wave*64 + 256*i)*16);
    }
    #pragma unroll
    for (int i = 0; i < 2; i++){
      int u = tid + 256*i;
      int r = u >> 3, cpos = u & 7, cg = cpos ^ (r & 7);
      load_lds_16B(&Bt[(size_t)(n0 + r) * K + kt + cg*8], (char*)Bs + (wave*64 + 256*i)*16);
    }
    __syncthreads();
    #pragma unroll
    for (int kk = 0; kk < 2; kk++){
      bf16x8 af[2], bfr[4];
      #pragma unroll
      for (int t = 0; t < 2; t++){
        int row = wm + t*16 + l16, cpos = (kk*4 + lq) ^ (l16 & 7);
        af[t] = *reinterpret_cast<bf16x8*>(&As[row*64 + cpos*8]);
      }
      #pragma unroll
      for (int t = 0; t < 4; t++){
        int row = t*16 + l16, cpos = (kk*4 + lq) ^ (l16 & 7);
        bfr[t] = *reinterpret_cast<bf16x8*>(&Bs[row*64 + cpos*8]);
      }
      #pragma unroll
      for (int ti = 0; ti < 2; ti++)
        #pragma unroll
        for (int tj = 0; tj < 4; tj++)
          acc[ti][tj] = __builtin_amdgcn_mfma_f32_16x16x32_bf16(af[ti], bfr[tj], acc[ti][tj], 0, 0, 0);
    }
  }
  #pragma unroll
  for (int ti = 0; ti < 2; ti++){
    #pragma unroll
    for (int tj = 0; tj < 4; tj++){
      int col = n0 + tj*16 + l16;
      float bvv = bias[col];
      #pragma unroll
      for (int r = 0; r < 4; r++){
        int row = m0 + wm + ti*16 + lq*4 + r;
        C[(size_t)row * N + col] = acc[ti][tj][r] + bvv;
      }
    }
  }
}

// ---------------- per-head V transpose: vh[b*2048+s][h*64+d] -> Vt[(b*16+h)*64+d][s] ----------------
__global__ __launch_bounds__(256) void vtrans_kernel(const bf16_t* __restrict__ vh,
                                                     bf16_t* __restrict__ Vt){
  __shared__ bf16_t T[64][72];
  int tid = threadIdx.x;
  int s0 = blockIdx.x * 64, h = blockIdx.y, b = blockIdx.z;
  #pragma unroll
  for (int i = 0; i < 2; i++){
    int u = tid + 256*i;
    int r = u >> 3, c = (u & 7) * 8;
    *reinterpret_cast<uint4*>(&T[r][c]) =
      *reinterpret_cast<const uint4*>(&vh[(size_t)(b*2048 + s0 + r) * 1024 + h*64 + c]);
  }
  __syncthreads();
  #pragma unroll
  for (int i = 0; i < 2; i++){
    int u = tid + 256*i;
    int d = u >> 3, cs = (u & 7) * 8;
    bf16_t t8[8];
    #pragma unroll
    for (int j = 0; j < 8; j++) t8[j] = T[cs + j][d];
    *reinterpret_cast<uint4*>(&Vt[(size_t)((b*16 + h)*64 + d) * 2048 + s0 + cs]) =
      *reinterpret_cast<uint4*>(t8);
  }
}

// ---------------- flash attention v8: 128 q-rows/block, 8 waves (TLP) ----------------
// Grid (16,16,2) = 512 blocks x 512 threads; 8 waves = (qo 0..3, khalf 0..1).
// 2 blocks/CU x 8 waves = 16 waves/CU = 4 waves/SIMD (2x v7's TLP); staging shared by
// 8 waves (1 K-load + 1 V-load per thread per tile). Per-wave body = verified v5/v6
// single-subtile form: mask C-init from prescaled global floats -> QK 4-chain ->
// exp -> shfl_xor P-transpose -> PV + ones-MFMA row-sum. Prefetch-then-drain single
// __syncthreads per tile (verified v7 loop). launch_bounds(512,4) caps VGPR at 128.
// LDS: K dbuf 16K + V dbuf 16K + Lsum[128]; epilogue Opart (4 qo x 8KB) overlays bufs.
__global__ __launch_bounds__(512, 4) void attn_kernel(const bf16_t* __restrict__ qp,
                                                      const bf16_t* __restrict__ kp,
                                                      const bf16_t* __restrict__ vt,
                                                      const float* __restrict__ ms,
                                                      bf16_t* __restrict__ ctx){
  const int S = 2048, D = 1024, HD = 64;
  __shared__ __align__(16) char smem[33280];
  // K bufs [0,16384), V bufs [16384,32768), Lsum [32768, +512)
  float* Lsum  = (float*)(smem + 32768);   // [128]
  float* Opart = (float*)smem;             // epilogue overlay: 32 KB
  int tid = threadIdx.x, wave = tid >> 6, lane = tid & 63;
  int l32 = lane & 31, H = lane >> 5;
  int qo = wave >> 1, khalf = wave & 1;
  int qt = blockIdx.x, h = blockIdx.y, b = blockIdx.z;
  const bf16_t* Qg = qp + (size_t)b*S*D + h*HD;
  const bf16_t* Kg = kp + (size_t)b*S*D + h*HD;
  const bf16_t* Vg = vt + (size_t)(b*16 + h)*HD*S;
  const float*  Mg = ms + (size_t)b*S;

  auto stage = [&](int kt, int bsel){
    char* Kd = smem + bsel*8192;
    char* Vd = smem + 16384 + bsel*8192;
    int r = tid >> 3, c = tid & 7, cg = c ^ (r & 7);
    int ldsoff = wave * 1024;  // wave-uniform base; HW adds lane*16
    load_lds_16B(&Kg[(size_t)(kt + r) * D + cg*8], Kd + ldsoff);
    load_lds_16B(&Vg[(size_t)r * S + kt + cg*8], Vd + ldsoff);
  };

  // Q fragments straight from global: B-operand, lane n=qrow, k=d=16s+8H+j
  int qrow = qt*128 + qo*32 + l32;
  bf16x8 qf[4];
  #pragma unroll
  for (int s = 0; s < 4; s++)
    qf[s] = *reinterpret_cast<const bf16x8*>(&Qg[(size_t)qrow * D + s*16 + 8*H]);

  f32x16 o0 = zero16(), o1 = zero16(), lmm = zero16();
  int krow = khalf*32 + l32;

  pk16 ones;
  ones.h[0].x = 0x3F803F80u; ones.h[0].y = 0x3F803F80u;
  ones.h[1].x = 0x3F803F80u; ones.h[1].y = 0x3F803F80u;

  stage(0, 0);
  __syncthreads();
  int cur = 0;

  for (int kt = 0; kt < S; kt += 64){
    // mask bias loads FIRST (before stage issue) so their wait leaves prefetch in flight
    cinit_t ci;
    #pragma unroll
    for (int g = 0; g < 4; g++)
      ci.f4[g] = *reinterpret_cast<const float4*>(&Mg[kt + khalf*32 + 8*g + 4*H]);

    if (kt + 64 < S) stage(kt + 64, cur ^ 1);

    bf16_t* Ks  = (bf16_t*)(smem + cur*8192);
    bf16_t* Vts = (bf16_t*)(smem + 16384 + cur*8192);

    // QK: one 32x32 Sc^T tile (this wave's 32 keys x its 32 q), chained over d=64
    f32x16 sc;
    #pragma unroll
    for (int s = 0; s < 4; s++){
      int cp = (2*s + H) ^ (l32 & 7);  // krow&7 == l32&7
      bf16x8 kf = *reinterpret_cast<bf16x8*>(&Ks[krow*64 + cp*8]);
      if (s == 0) sc = __builtin_amdgcn_mfma_f32_32x32x16_bf16(kf, qf[0], ci.v, 0, 0, 0);
      else        sc = __builtin_amdgcn_mfma_f32_32x32x16_bf16(kf, qf[s], sc, 0, 0, 0);
    }
    // exp; C-layout: lane owns q-col l32; tile-key = khalf*32 + 8g + 4H + r (reg=4g+r)
    pk8 grp[4];
    #pragma unroll
    for (int g = 0; g < 4; g++){
      float p0 = EXP2F(sc[4*g+0]);
      float p1 = EXP2F(sc[4*g+1]);
      float p2 = EXP2F(sc[4*g+2]);
      float p3 = EXP2F(sc[4*g+3]);
      pk8 w;
      w.b4[0] = (bf16_t)p0; w.b4[1] = (bf16_t)p1; w.b4[2] = (bf16_t)p2; w.b4[3] = (bf16_t)p3;
      grp[g] = w;
    }
    // PV with register transpose; window kk covers tile-keys khalf*32 + 16kk + 8H + j
    #pragma unroll
    for (int kk = 0; kk < 2; kk++){
      uint2 ga = grp[2*kk].u2;
      uint2 gb = grp[2*kk+1].u2;
      uint2 send = H ? ga : gb;
      uint2 recv;
      recv.x = (unsigned)__shfl_xor((int)send.x, 32);
      recv.y = (unsigned)__shfl_xor((int)send.y, 32);
      pk16 fr;
      fr.h[0] = H ? recv : ga;
      fr.h[1] = H ? gb : recv;
      int cp = (4*khalf + 2*kk + H) ^ (l32 & 7);
      bf16x8 vf0 = *reinterpret_cast<bf16x8*>(&Vts[l32*64 + cp*8]);
      bf16x8 vf1 = *reinterpret_cast<bf16x8*>(&Vts[(32 + l32)*64 + cp*8]);
      o0  = __builtin_amdgcn_mfma_f32_32x32x16_bf16(fr.b8, vf0, o0, 0, 0, 0);
      o1  = __builtin_amdgcn_mfma_f32_32x32x16_bf16(fr.b8, vf1, o1, 0, 0, 0);
      lmm = __builtin_amdgcn_mfma_f32_32x32x16_bf16(fr.b8, ones.b8, lmm, 0, 0, 0);
    }
    __syncthreads();
    cur ^= 1;
  }

  // epilogue: combine k-halves through LDS (overlays K/V bufs), normalize, store
  if (khalf == 1){
    #pragma unroll
    for (int reg = 0; reg < 16; reg++){
      Opart[qo*2048 + reg*64 + lane]        = o0[reg];
      Opart[qo*2048 + 1024 + reg*64 + lane] = o1[reg];
    }
    if (l32 == 0){
      #pragma unroll
      for (int reg = 0; reg < 16; reg++)
        Lsum[qo*32 + (reg & 3) + 8*(reg >> 2) + 4*H] = lmm[reg];
    }
  }
  __syncthreads();
  if (khalf == 0){
    #pragma unroll
    for (int reg = 0; reg < 16; reg++){
      o0[reg] += Opart[qo*2048 + reg*64 + lane];
      o1[reg] += Opart[qo*2048 + 1024 + reg*64 + lane];
    }
    #pragma unroll
    for (int g = 0; g < 4; g++){
      #pragma unroll
      for (int r = 0; r < 4; r++){
        float lf = lmm[4*g + r] + Lsum[qo*32 + 8*g + 4*H + r];
        float inv = 1.f / lf;
        int grow = qt*128 + qo*32 + 8*g + 4*H + r;
        size_t base = (size_t)(b*S + grow) * D + h*HD;
        ctx[base + l32]      = (bf16_t)(o0[4*g + r] * inv);
        ctx[base + 32 + l32] = (bf16_t)(o1[4*g + r] * inv);
      }
    }
  }
}

extern "C" void kernel_launch(void* const* d_in, const int* in_sizes, int n_in,
                              void* d_out, int out_size, void* d_ws, size_t ws_size,
                              hipStream_t stream){
  const float* q    = (const float*)d_in[0];
  const float* k    = (const float*)d_in[1];
  const float* v    = (const float*)d_in[2];
  const float* mask = (const float*)d_in[3];
  const float* Wq   = (const float*)d_in[4];
  const float* bq   = (const float*)d_in[5];
  const float* Wk   = (const float*)d_in[6];
  const float* bk   = (const float*)d_in[7];
  const float* Wv   = (const float*)d_in[8];
  const float* bv   = (const float*)d_in[9];
  const float* Wo   = (const float*)d_in[10];
  const float* bo   = (const float*)d_in[11];

  char* ws = (char*)d_ws;
  bf16_t* qp    = (bf16_t*)(ws);               // [0, 8 MiB)
  bf16_t* kp    = (bf16_t*)(ws + 8388608);     // [8, 16)
  bf16_t* vh    = (bf16_t*)(ws + 16777216);    // [16, 24)
  bf16_t* Wcat  = (bf16_t*)(ws + 25165824);    // [24, 30)
  bf16_t* Wot   = (bf16_t*)(ws + 31457280);    // [30, 32)
  bf16_t* Vt    = (bf16_t*)(ws + 33554432);    // [32, 40)
  bf16_t* ctx   = (bf16_t*)(ws + 41943040);    // [40, 48)
  bf16_t* qkvin = (bf16_t*)(ws + 33554432);    // [32, 56) path A only; dead before Vt/ctx live
  float*  msbuf = (float*)(ws + 16777216);     // 16 KB, overlays vh (dead after vtrans)

  wtrans4_kernel<<<dim3(32,32,4), dim3(32,8), 0, stream>>>(Wq, Wk, Wv, Wo, Wcat, Wot);
  if (ws_size >= 58720256){
    cast3_kernel<<<dim3(4096,3), 256, 0, stream>>>(q, k, v, qkvin);
    gemm_qkv_bf<<<dim3(24,32), 256, 0, stream>>>(qkvin, Wcat, bq, bk, bv, qp, kp, vh);
  } else {
    gemm_qkv_f32<<<dim3(24,32), 256, 0, stream>>>(q, k, v, Wcat, bq, bk, bv, qp, kp, vh);
  }
  vtrans_kernel<<<dim3(32,16,2), 256, 0, stream>>>(vh, Vt);
  mask_scale_kernel<<<dim3(16), 256, 0, stream>>>(mask, msbuf);
  attn_kernel<<<dim3(16,16,2), 512, 0, stream>>>(qp, kp, Vt, msbuf, ctx);
  gemm_out<<<dim3(16,32), 256, 0, stream>>>(ctx, Wot, bo, (float*)d_out);
}

// Round 6
// 231.951 us; speedup vs baseline: 1.0173x; 1.0173x over previous
//
#include <hip/hip_runtime.h>
#include <math.h>

typedef __bf16 bf16_t;
typedef __bf16 bf16x8 __attribute__((ext_vector_type(8)));
typedef __bf16 bf16x4v __attribute__((ext_vector_type(4)));
typedef float f32x4 __attribute__((ext_vector_type(4)));
typedef float f32x16 __attribute__((ext_vector_type(16)));

#define LOG2E 1.4426950408889634f
#define MBIAS_C (-1e12f * LOG2E)

#if __has_builtin(__builtin_amdgcn_exp2f)
#define EXP2F(x) __builtin_amdgcn_exp2f(x)
#else
#define EXP2F(x) exp2f(x)
#endif

typedef __attribute__((address_space(1))) const unsigned int g_u32;
typedef __attribute__((address_space(3))) unsigned int l_u32;
__device__ __forceinline__ void load_lds_16B(const void* g, void* l){
  __builtin_amdgcn_global_load_lds((g_u32*)g, (l_u32*)l, 16, 0, 0);
}

__device__ __forceinline__ f32x16 zero16(){
  f32x16 z;
  #pragma unroll
  for (int i = 0; i < 16; i++) z[i] = 0.f;
  return z;
}

typedef union { bf16x4v b4; uint2 u2; } pk8;
typedef union { uint2 h[2]; bf16x8 b8; } pk16;
typedef union { float4 f4[4]; f32x16 v; } cinit_t;

// ---------------- cast q,k,v fp32 -> bf16 planes ----------------
__global__ __launch_bounds__(256) void cast3_kernel(const float* __restrict__ q,
                                                    const float* __restrict__ k,
                                                    const float* __restrict__ v,
                                                    bf16_t* __restrict__ out){
  int z = blockIdx.y;
  const float* x = (z == 0) ? q : (z == 1) ? k : v;
  int i = blockIdx.x * 256 + threadIdx.x;
  float4 f = reinterpret_cast<const float4*>(x)[i];
  bf16x4v w;
  w[0] = (bf16_t)f.x; w[1] = (bf16_t)f.y; w[2] = (bf16_t)f.z; w[3] = (bf16_t)f.w;
  reinterpret_cast<bf16x4v*>(out + (size_t)z * 4194304)[i] = w;
}

// ---------------- mask prescale: ms[i] = mask[i] * (-1e12 * log2e) ----------------
__global__ __launch_bounds__(256) void mask_scale_kernel(const float* __restrict__ mask,
                                                         float* __restrict__ ms){
  int i = blockIdx.x * 256 + threadIdx.x;
  ms[i] = mask[i] * MBIAS_C;
}

// ---------------- weight transpose+cast ----------------
__global__ __launch_bounds__(256) void wtrans4_kernel(const float* __restrict__ Wq,
                                                      const float* __restrict__ Wk,
                                                      const float* __restrict__ Wv,
                                                      const float* __restrict__ Wo,
                                                      bf16_t* __restrict__ Wcat,
                                                      bf16_t* __restrict__ Wot){
  __shared__ float T[32][33];
  int z = blockIdx.z;
  const float* W = (z == 0) ? Wq : (z == 1) ? Wk : (z == 2) ? Wv : Wo;
  bf16_t* dst = (z < 3) ? (Wcat + (size_t)z * 1024 * 1024) : Wot;
  int x = threadIdx.x, y = threadIdx.y;
  int k0 = blockIdx.y * 32, n0 = blockIdx.x * 32;
  #pragma unroll
  for (int i = 0; i < 4; i++) T[y + 8*i][x] = W[(size_t)(k0 + y + 8*i) * 1024 + n0 + x];
  __syncthreads();
  #pragma unroll
  for (int i = 0; i < 4; i++) dst[(size_t)(n0 + y + 8*i) * 1024 + k0 + x] = (bf16_t)T[x][y + 8*i];
}

// ---------------- shared epilogue for QKV GEMMs: write q/k/v planes ----------------
__device__ __forceinline__ void qkv_epilogue(f32x4 (&acc)[4][4], int seg, int n0g, int m0,
                                             int wm, int wn, int l16, int lq,
                                             const float* bias, bf16_t* qp, bf16_t* kp,
                                             bf16_t* vh){
  bf16_t* Cp = (seg == 0) ? qp : (seg == 1) ? kp : vh;
  float scale = (seg == 0) ? 0.125f * LOG2E : 1.0f;  // fold softmax scale + log2e into Q
  #pragma unroll
  for (int ti = 0; ti < 4; ti++){
    #pragma unroll
    for (int tj = 0; tj < 4; tj++){
      int col = (n0g + wn + tj*16 + l16) & 1023;
      float bvv = bias[col];
      #pragma unroll
      for (int r = 0; r < 4; r++){
        int row = m0 + wm + ti*16 + lq*4 + r;
        Cp[(size_t)row * 1024 + col] = (bf16_t)((acc[ti][tj][r] + bvv) * scale);
      }
    }
  }
}

// ---------------- fused QKV GEMM, all-bf16 (path A) ----------------
__global__ __launch_bounds__(256) void gemm_qkv_bf(const bf16_t* __restrict__ qkvin,
                                                   const bf16_t* __restrict__ Wcat,
                                                   const float* __restrict__ bq,
                                                   const float* __restrict__ bk,
                                                   const float* __restrict__ bv,
                                                   bf16_t* __restrict__ qp,
                                                   bf16_t* __restrict__ kp,
                                                   bf16_t* __restrict__ vh){
  const int K = 1024;
  __shared__ __align__(16) bf16_t As[128*32];
  __shared__ __align__(16) bf16_t Bs[128*32];
  int tid = threadIdx.x, wave = tid >> 6, lane = tid & 63;
  int l16 = lane & 15, lq = lane >> 4;
  int n0g = blockIdx.x * 128;
  int seg = n0g >> 10;
  const bf16_t* A   = qkvin + (size_t)seg * 4194304;
  const float* bias = (seg == 0) ? bq : (seg == 1) ? bk : bv;
  int m0 = blockIdx.y * 128;
  int wm = (wave >> 1) * 64, wn = (wave & 1) * 64;
  int cposR = lq ^ ((l16 >> 2) & 3);
  f32x4 acc[4][4] = {};
  for (int kt = 0; kt < K; kt += 32){
    __syncthreads();
    #pragma unroll
    for (int i = 0; i < 2; i++){
      int u = tid + 256*i;
      int r = u >> 2, cpos = u & 3, cg = cpos ^ ((r >> 2) & 3);
      int ldsoff = (wave*64 + 256*i) * 16;
      load_lds_16B(&A[(size_t)(m0 + r) * K + kt + cg*8], (char*)As + ldsoff);
      load_lds_16B(&Wcat[(size_t)(n0g + r) * K + kt + cg*8], (char*)Bs + ldsoff);
    }
    __syncthreads();
    bf16x8 af[4], bfr[4];
    #pragma unroll
    for (int t = 0; t < 4; t++) af[t]  = *reinterpret_cast<bf16x8*>(&As[(wm + t*16 + l16)*32 + cposR*8]);
    #pragma unroll
    for (int t = 0; t < 4; t++) bfr[t] = *reinterpret_cast<bf16x8*>(&Bs[(wn + t*16 + l16)*32 + cposR*8]);
    #pragma unroll
    for (int ti = 0; ti < 4; ti++)
      #pragma unroll
      for (int tj = 0; tj < 4; tj++)
        acc[ti][tj] = __builtin_amdgcn_mfma_f32_16x16x32_bf16(af[ti], bfr[tj], acc[ti][tj], 0, 0, 0);
  }
  qkv_epilogue(acc, seg, n0g, m0, wm, wn, l16, lq, bias, qp, kp, vh);
}

// ---------------- fused QKV GEMM, fp32-A fused-cvt (path B fallback) ----------------
__global__ __launch_bounds__(256) void gemm_qkv_f32(const float* __restrict__ qi,
                                                    const float* __restrict__ ki,
                                                    const float* __restrict__ vi,
                                                    const bf16_t* __restrict__ Wcat,
                                                    const float* __restrict__ bq,
                                                    const float* __restrict__ bk,
                                                    const float* __restrict__ bv,
                                                    bf16_t* __restrict__ qp,
                                                    bf16_t* __restrict__ kp,
                                                    bf16_t* __restrict__ vh){
  const int K = 1024;
  __shared__ __align__(16) float  Asf[128*32];
  __shared__ __align__(16) bf16_t Bs[128*32];
  int tid = threadIdx.x, wave = tid >> 6, lane = tid & 63;
  int l16 = lane & 15, lq = lane >> 4;
  int n0g = blockIdx.x * 128;
  int seg = n0g >> 10;
  const float* A    = (seg == 0) ? qi : (seg == 1) ? ki : vi;
  const float* bias = (seg == 0) ? bq : (seg == 1) ? bk : bv;
  int m0 = blockIdx.y * 128;
  int wm = (wave >> 1) * 64, wn = (wave & 1) * 64;
  int cposR = lq ^ ((l16 >> 2) & 3);
  int ca0 = (2*lq)     ^ (l16 & 7);
  int ca1 = (2*lq + 1) ^ (l16 & 7);
  f32x4 acc[4][4] = {};
  for (int kt = 0; kt < K; kt += 32){
    __syncthreads();
    #pragma unroll
    for (int i = 0; i < 4; i++){
      int u = tid + 256*i;
      int r = u >> 3, cpos = u & 7, cg = cpos ^ (r & 7);
      load_lds_16B(&A[(size_t)(m0 + r) * K + kt + cg*4], (char*)Asf + (wave*64 + 256*i)*16);
    }
    #pragma unroll
    for (int i = 0; i < 2; i++){
      int u = tid + 256*i;
      int r = u >> 2, cpos = u & 3, cg = cpos ^ ((r >> 2) & 3);
      load_lds_16B(&Wcat[(size_t)(n0g + r) * K + kt + cg*8], (char*)Bs + (wave*64 + 256*i)*16);
    }
    __syncthreads();
    bf16x8 af[4], bfr[4];
    #pragma unroll
    for (int t = 0; t < 4; t++){
      int row = wm + t*16 + l16;
      f32x4 x0 = *reinterpret_cast<f32x4*>(&Asf[row*32 + ca0*4]);
      f32x4 x1 = *reinterpret_cast<f32x4*>(&Asf[row*32 + ca1*4]);
      bf16x8 a;
      a[0] = (bf16_t)x0[0]; a[1] = (bf16_t)x0[1]; a[2] = (bf16_t)x0[2]; a[3] = (bf16_t)x0[3];
      a[4] = (bf16_t)x1[0]; a[5] = (bf16_t)x1[1]; a[6] = (bf16_t)x1[2]; a[7] = (bf16_t)x1[3];
      af[t] = a;
    }
    #pragma unroll
    for (int t = 0; t < 4; t++) bfr[t] = *reinterpret_cast<bf16x8*>(&Bs[(wn + t*16 + l16)*32 + cposR*8]);
    #pragma unroll
    for (int ti = 0; ti < 4; ti++)
      #pragma unroll
      for (int tj = 0; tj < 4; tj++)
        acc[ti][tj] = __builtin_amdgcn_mfma_f32_16x16x32_bf16(af[ti], bfr[tj], acc[ti][tj], 0, 0, 0);
  }
  qkv_epilogue(acc, seg, n0g, m0, wm, wn, l16, lq, bias, qp, kp, vh);
}

// ---------------- output GEMM: d_out = ctx @ Wot^T + bo, fp32 out ----------------
__global__ __launch_bounds__(256) void gemm_out(const bf16_t* __restrict__ A,
                                                const bf16_t* __restrict__ Bt,
                                                const float* __restrict__ bias,
                                                float* __restrict__ C){
  const int K = 1024, N = 1024;
  __shared__ __align__(16) bf16_t As[128*64];
  __shared__ __align__(16) bf16_t Bs[64*64];
  int tid = threadIdx.x, wave = tid >> 6, lane = tid & 63;
  int l16 = lane & 15, lq = lane >> 4;
  int m0 = blockIdx.y * 128, n0 = blockIdx.x * 64;
  int wm = wave * 32;
  f32x4 acc[2][4] = {};
  for (int kt = 0; kt < K; kt += 64){
    __syncthreads();
    #pragma unroll
    for (int i = 0; i < 4; i++){
      int u = tid + 256*i;
      int r = u >> 3, cpos = u & 7, cg = cpos ^ (r & 7);
      load_lds_16B(&A[(size_t)(m0 + r) * K + kt + cg*8], (char*)As + (wave*64 + 256*i)*16);
    }
    #pragma unroll
    for (int i = 0; i < 2; i++){
      int u = tid + 256*i;
      int r = u >> 3, cpos = u & 7, cg = cpos ^ (r & 7);
      load_lds_16B(&Bt[(size_t)(n0 + r) * K + kt + cg*8], (char*)Bs + (wave*64 + 256*i)*16);
    }
    __syncthreads();
    #pragma unroll
    for (int kk = 0; kk < 2; kk++){
      bf16x8 af[2], bfr[4];
      #pragma unroll
      for (int t = 0; t < 2; t++){
        int row = wm + t*16 + l16, cpos = (kk*4 + lq) ^ (l16 & 7);
        af[t] = *reinterpret_cast<bf16x8*>(&As[row*64 + cpos*8]);
      }
      #pragma unroll
      for (int t = 0; t < 4; t++){
        int row = t*16 + l16, cpos = (kk*4 + lq) ^ (l16 & 7);
        bfr[t] = *reinterpret_cast<bf16x8*>(&Bs[row*64 + cpos*8]);
      }
      #pragma unroll
      for (int ti = 0; ti < 2; ti++)
        #pragma unroll
        for (int tj = 0; tj < 4; tj++)
          acc[ti][tj] = __builtin_amdgcn_mfma_f32_16x16x32_bf16(af[ti], bfr[tj], acc[ti][tj], 0, 0, 0);
    }
  }
  #pragma unroll
  for (int ti = 0; ti < 2; ti++){
    #pragma unroll
    for (int tj = 0; tj < 4; tj++){
      int col = n0 + tj*16 + l16;
      float bvv = bias[col];
      #pragma unroll
      for (int r = 0; r < 4; r++){
        int row = m0 + wm + ti*16 + lq*4 + r;
        C[(size_t)row * N + col] = acc[ti][tj][r] + bvv;
      }
    }
  }
}

// ---------------- per-head V transpose: vh[b*2048+s][h*64+d] -> Vt[(b*16+h)*64+d][s] ----------------
__global__ __launch_bounds__(256) void vtrans_kernel(const bf16_t* __restrict__ vh,
                                                     bf16_t* __restrict__ Vt){
  __shared__ bf16_t T[64][72];
  int tid = threadIdx.x;
  int s0 = blockIdx.x * 64, h = blockIdx.y, b = blockIdx.z;
  #pragma unroll
  for (int i = 0; i < 2; i++){
    int u = tid + 256*i;
    int r = u >> 3, c = (u & 7) * 8;
    *reinterpret_cast<uint4*>(&T[r][c]) =
      *reinterpret_cast<const uint4*>(&vh[(size_t)(b*2048 + s0 + r) * 1024 + h*64 + c]);
  }
  __syncthreads();
  #pragma unroll
  for (int i = 0; i < 2; i++){
    int u = tid + 256*i;
    int d = u >> 3, cs = (u & 7) * 8;
    bf16_t t8[8];
    #pragma unroll
    for (int j = 0; j < 8; j++) t8[j] = T[cs + j][d];
    *reinterpret_cast<uint4*>(&Vt[(size_t)((b*16 + h)*64 + d) * 2048 + s0 + cs]) =
      *reinterpret_cast<uint4*>(t8);
  }
}

// ---------------- flash attention v9: de-lockstepped pipeline ----------------
// Geometry = v8 (128 q/block, 8 waves=(qo,khalf), 512 thr, 2 blocks/CU). Changes:
//  - 4 K-bufs + 4 V-bufs, depth-2 prefetch: per iter {stage T+2,T+3 -> compute T ->
//    compute T+1 -> barrier}. ONE barrier+drain per 128 keys (half of v8); stage
//    latency covered by 2 tile-computes; waves drift across QK/exp/PV phases within
//    the 2-tile window -> MFMA/VALU/DS pipes overlap across waves.
//  - mask f32 staged to LDS once (8 KB): per-tile ci reads are quarter-wave-broadcast
//    ds_reads, off the VMEM path (vmcnt = prefetch only).
//  - s_setprio(1) around the two MFMA clusters (T5; effective now that waves drift).
// LDS: K 4x8K [0,32768) + V 4x8K [32768,65536) + mask [65536,73728) + Lsum [73728,+512)
// = 74240 B -> 2 blocks/CU. Epilogue Opart (32 KB) overlays K bufs.
__global__ __launch_bounds__(512, 4) void attn_kernel(const bf16_t* __restrict__ qp,
                                                      const bf16_t* __restrict__ kp,
                                                      const bf16_t* __restrict__ vt,
                                                      const float* __restrict__ ms,
                                                      bf16_t* __restrict__ ctx){
  const int S = 2048, D = 1024, HD = 64;
  __shared__ __align__(16) char smem[74240];
  float* Lsum  = (float*)(smem + 73728);   // [128]
  float* Opart = (float*)smem;             // epilogue overlay: 32 KB
  const float* Ml = (const float*)(smem + 65536);  // mask f32 [2048]
  int tid = threadIdx.x, wave = tid >> 6, lane = tid & 63;
  int l32 = lane & 31, H = lane >> 5;
  int qo = wave >> 1, khalf = wave & 1;
  int qt = blockIdx.x, h = blockIdx.y, b = blockIdx.z;
  const bf16_t* Qg = qp + (size_t)b*S*D + h*HD;
  const bf16_t* Kg = kp + (size_t)b*S*D + h*HD;
  const bf16_t* Vg = vt + (size_t)(b*16 + h)*HD*S;
  const float*  Mg = ms + (size_t)b*S;

  auto stage = [&](int kt, int bsel){
    char* Kd = smem + bsel*8192;
    char* Vd = smem + 32768 + bsel*8192;
    int r = tid >> 3, c = tid & 7, cg = c ^ (r & 7);
    int ldsoff = wave * 1024;  // wave-uniform base; HW adds lane*16
    load_lds_16B(&Kg[(size_t)(kt + r) * D + cg*8], Kd + ldsoff);
    load_lds_16B(&Vg[(size_t)r * S + kt + cg*8], Vd + ldsoff);
  };

  // Q fragments straight from global: B-operand, lane n=qrow, k=d=16s+8H+j
  int qrow = qt*128 + qo*32 + l32;
  bf16x8 qf[4];
  #pragma unroll
  for (int s = 0; s < 4; s++)
    qf[s] = *reinterpret_cast<const bf16x8*>(&Qg[(size_t)qrow * D + s*16 + 8*H]);

  f32x16 o0 = zero16(), o1 = zero16(), lmm = zero16();
  int krow = khalf*32 + l32;

  pk16 ones;
  ones.h[0].x = 0x3F803F80u; ones.h[0].y = 0x3F803F80u;
  ones.h[1].x = 0x3F803F80u; ones.h[1].y = 0x3F803F80u;

  // prologue: mask row (8 KB, 1 load/thread) + tiles 0,1
  load_lds_16B(&Mg[(size_t)tid*4], smem + 65536 + wave*1024);
  stage(0, 0);
  stage(64, 1);
  __syncthreads();

  auto tile_compute = [&](int kt, int cur){
    bf16_t* Ks  = (bf16_t*)(smem + cur*8192);
    bf16_t* Vts = (bf16_t*)(smem + 32768 + cur*8192);
    // mask C-init from LDS (quarter-wave broadcast ds_reads)
    cinit_t ci;
    #pragma unroll
    for (int g = 0; g < 4; g++)
      ci.f4[g] = *reinterpret_cast<const float4*>(&Ml[kt + khalf*32 + 8*g + 4*H]);
    // QK: one 32x32 Sc^T tile, chained over d=64, mask rides in as C operand
    f32x16 sc;
    __builtin_amdgcn_s_setprio(1);
    #pragma unroll
    for (int s = 0; s < 4; s++){
      int cp = (2*s + H) ^ (l32 & 7);  // krow&7 == l32&7
      bf16x8 kf = *reinterpret_cast<bf16x8*>(&Ks[krow*64 + cp*8]);
      if (s == 0) sc = __builtin_amdgcn_mfma_f32_32x32x16_bf16(kf, qf[0], ci.v, 0, 0, 0);
      else        sc = __builtin_amdgcn_mfma_f32_32x32x16_bf16(kf, qf[s], sc, 0, 0, 0);
    }
    __builtin_amdgcn_s_setprio(0);
    // exp; C-layout: lane owns q-col l32; tile-key = khalf*32 + 8g + 4H + r (reg=4g+r)
    pk8 grp[4];
    #pragma unroll
    for (int g = 0; g < 4; g++){
      float p0 = EXP2F(sc[4*g+0]);
      float p1 = EXP2F(sc[4*g+1]);
      float p2 = EXP2F(sc[4*g+2]);
      float p3 = EXP2F(sc[4*g+3]);
      pk8 w;
      w.b4[0] = (bf16_t)p0; w.b4[1] = (bf16_t)p1; w.b4[2] = (bf16_t)p2; w.b4[3] = (bf16_t)p3;
      grp[g] = w;
    }
    // PV with register transpose; window kk covers tile-keys khalf*32 + 16kk + 8H + j
    #pragma unroll
    for (int kk = 0; kk < 2; kk++){
      uint2 ga = grp[2*kk].u2;
      uint2 gb = grp[2*kk+1].u2;
      uint2 send = H ? ga : gb;
      uint2 recv;
      recv.x = (unsigned)__shfl_xor((int)send.x, 32);
      recv.y = (unsigned)__shfl_xor((int)send.y, 32);
      pk16 fr;
      fr.h[0] = H ? recv : ga;
      fr.h[1] = H ? gb : recv;
      int cp = (4*khalf + 2*kk + H) ^ (l32 & 7);
      bf16x8 vf0 = *reinterpret_cast<bf16x8*>(&Vts[l32*64 + cp*8]);
      bf16x8 vf1 = *reinterpret_cast<bf16x8*>(&Vts[(32 + l32)*64 + cp*8]);
      __builtin_amdgcn_s_setprio(1);
      o0  = __builtin_amdgcn_mfma_f32_32x32x16_bf16(fr.b8, vf0, o0, 0, 0, 0);
      o1  = __builtin_amdgcn_mfma_f32_32x32x16_bf16(fr.b8, vf1, o1, 0, 0, 0);
      lmm = __builtin_amdgcn_mfma_f32_32x32x16_bf16(fr.b8, ones.b8, lmm, 0, 0, 0);
      __builtin_amdgcn_s_setprio(0);
    }
  };

  // main loop: 2 tiles per iter, depth-2 prefetch, ONE barrier per iter.
  // Tile T lives in buf T&3. stage(T+2) overwrites buf holding T-2 (reads done
  // before previous barrier); reads of T,T+1 use stages drained at previous barrier.
  #pragma unroll 2
  for (int it = 0; it < 16; ++it){
    int kt = it * 128;
    if (it < 15){
      stage(kt + 128, (2*it + 2) & 3);
      stage(kt + 192, (2*it + 3) & 3);
    }
    tile_compute(kt,      (2*it) & 3);
    tile_compute(kt + 64, (2*it + 1) & 3);
    __syncthreads();
  }

  // epilogue: combine k-halves through LDS (overlays K bufs), normalize, store
  if (khalf == 1){
    #pragma unroll
    for (int reg = 0; reg < 16; reg++){
      Opart[qo*2048 + reg*64 + lane]        = o0[reg];
      Opart[qo*2048 + 1024 + reg*64 + lane] = o1[reg];
    }
    if (l32 == 0){
      #pragma unroll
      for (int reg = 0; reg < 16; reg++)
        Lsum[qo*32 + (reg & 3) + 8*(reg >> 2) + 4*H] = lmm[reg];
    }
  }
  __syncthreads();
  if (khalf == 0){
    #pragma unroll
    for (int reg = 0; reg < 16; reg++){
      o0[reg] += Opart[qo*2048 + reg*64 + lane];
      o1[reg] += Opart[qo*2048 + 1024 + reg*64 + lane];
    }
    #pragma unroll
    for (int g = 0; g < 4; g++){
      #pragma unroll
      for (int r = 0; r < 4; r++){
        float lf = lmm[4*g + r] + Lsum[qo*32 + 8*g + 4*H + r];
        float inv = 1.f / lf;
        int grow = qt*128 + qo*32 + 8*g + 4*H + r;
        size_t base = (size_t)(b*S + grow) * D + h*HD;
        ctx[base + l32]      = (bf16_t)(o0[4*g + r] * inv);
        ctx[base + 32 + l32] = (bf16_t)(o1[4*g + r] * inv);
      }
    }
  }
}

extern "C" void kernel_launch(void* const* d_in, const int* in_sizes, int n_in,
                              void* d_out, int out_size, void* d_ws, size_t ws_size,
                              hipStream_t stream){
  const float* q    = (const float*)d_in[0];
  const float* k    = (const float*)d_in[1];
  const float* v    = (const float*)d_in[2];
  const float* mask = (const float*)d_in[3];
  const float* Wq   = (const float*)d_in[4];
  const float* bq   = (const float*)d_in[5];
  const float* Wk   = (const float*)d_in[6];
  const float* bk   = (const float*)d_in[7];
  const float* Wv   = (const float*)d_in[8];
  const float* bv   = (const float*)d_in[9];
  const float* Wo   = (const float*)d_in[10];
  const float* bo   = (const float*)d_in[11];

  char* ws = (char*)d_ws;
  bf16_t* qp    = (bf16_t*)(ws);               // [0, 8 MiB)
  bf16_t* kp    = (bf16_t*)(ws + 8388608);     // [8, 16)
  bf16_t* vh    = (bf16_t*)(ws + 16777216);    // [16, 24)
  bf16_t* Wcat  = (bf16_t*)(ws + 25165824);    // [24, 30)
  bf16_t* Wot   = (bf16_t*)(ws + 31457280);    // [30, 32)
  bf16_t* Vt    = (bf16_t*)(ws + 33554432);    // [32, 40)
  bf16_t* ctx   = (bf16_t*)(ws + 41943040);    // [40, 48)
  bf16_t* qkvin = (bf16_t*)(ws + 33554432);    // [32, 56) path A only; dead before Vt/ctx live
  float*  msbuf = (float*)(ws + 16777216);     // 16 KB, overlays vh (dead after vtrans)

  wtrans4_kernel<<<dim3(32,32,4), dim3(32,8), 0, stream>>>(Wq, Wk, Wv, Wo, Wcat, Wot);
  if (ws_size >= 58720256){
    cast3_kernel<<<dim3(4096,3), 256, 0, stream>>>(q, k, v, qkvin);
    gemm_qkv_bf<<<dim3(24,32), 256, 0, stream>>>(qkvin, Wcat, bq, bk, bv, qp, kp, vh);
  } else {
    gemm_qkv_f32<<<dim3(24,32), 256, 0, stream>>>(q, k, v, Wcat, bq, bk, bv, qp, kp, vh);
  }
  vtrans_kernel<<<dim3(32,16,2), 256, 0, stream>>>(vh, Vt);
  mask_scale_kernel<<<dim3(16), 256, 0, stream>>>(mask, msbuf);
  attn_kernel<<<dim3(16,16,2), 512, 0, stream>>>(qp, kp, Vt, msbuf, ctx);
  gemm_out<<<dim3(16,32), 256, 0, stream>>>(ctx, Wot, bo, (float*)d_out);
}

// Round 7
// 231.794 us; speedup vs baseline: 1.0180x; 1.0007x over previous
//
#include <hip/hip_runtime.h>
#include <math.h>

typedef __bf16 bf16_t;
typedef __bf16 bf16x8 __attribute__((ext_vector_type(8)));
typedef __bf16 bf16x4v __attribute__((ext_vector_type(4)));
typedef float f32x4 __attribute__((ext_vector_type(4)));
typedef float f32x16 __attribute__((ext_vector_type(16)));

#define LOG2E 1.4426950408889634f
#define MBIAS_C (-1e12f * LOG2E)

#if __has_builtin(__builtin_amdgcn_exp2f)
#define EXP2F(x) __builtin_amdgcn_exp2f(x)
#else
#define EXP2F(x) exp2f(x)
#endif

typedef __attribute__((address_space(1))) const unsigned int g_u32;
typedef __attribute__((address_space(3))) unsigned int l_u32;
__device__ __forceinline__ void load_lds_16B(const void* g, void* l){
  __builtin_amdgcn_global_load_lds((g_u32*)g, (l_u32*)l, 16, 0, 0);
}

__device__ __forceinline__ f32x16 zero16(){
  f32x16 z;
  #pragma unroll
  for (int i = 0; i < 16; i++) z[i] = 0.f;
  return z;
}

typedef union { bf16x4v b4; uint2 u2; } pk8;
typedef union { uint2 h[2]; bf16x8 b8; } pk16;
typedef union { float4 f4[4]; f32x16 v; } cinit_t;

// ---------------- cast q,k,v fp32 -> bf16 planes ----------------
__global__ __launch_bounds__(256) void cast3_kernel(const float* __restrict__ q,
                                                    const float* __restrict__ k,
                                                    const float* __restrict__ v,
                                                    bf16_t* __restrict__ out){
  int z = blockIdx.y;
  const float* x = (z == 0) ? q : (z == 1) ? k : v;
  int i = blockIdx.x * 256 + threadIdx.x;
  float4 f = reinterpret_cast<const float4*>(x)[i];
  bf16x4v w;
  w[0] = (bf16_t)f.x; w[1] = (bf16_t)f.y; w[2] = (bf16_t)f.z; w[3] = (bf16_t)f.w;
  reinterpret_cast<bf16x4v*>(out + (size_t)z * 4194304)[i] = w;
}

// ---------------- weight transpose+cast ----------------
__global__ __launch_bounds__(256) void wtrans4_kernel(const float* __restrict__ Wq,
                                                      const float* __restrict__ Wk,
                                                      const float* __restrict__ Wv,
                                                      const float* __restrict__ Wo,
                                                      bf16_t* __restrict__ Wcat,
                                                      bf16_t* __restrict__ Wot){
  __shared__ float T[32][33];
  int z = blockIdx.z;
  const float* W = (z == 0) ? Wq : (z == 1) ? Wk : (z == 2) ? Wv : Wo;
  bf16_t* dst = (z < 3) ? (Wcat + (size_t)z * 1024 * 1024) : Wot;
  int x = threadIdx.x, y = threadIdx.y;
  int k0 = blockIdx.y * 32, n0 = blockIdx.x * 32;
  #pragma unroll
  for (int i = 0; i < 4; i++) T[y + 8*i][x] = W[(size_t)(k0 + y + 8*i) * 1024 + n0 + x];
  __syncthreads();
  #pragma unroll
  for (int i = 0; i < 4; i++) dst[(size_t)(n0 + y + 8*i) * 1024 + k0 + x] = (bf16_t)T[x][y + 8*i];
}

// ---------------- shared epilogue for QKV GEMMs: write q/k/v planes ----------------
__device__ __forceinline__ void qkv_epilogue(f32x4 (&acc)[4][4], int seg, int n0g, int m0,
                                             int wm, int wn, int l16, int lq,
                                             const float* bias, bf16_t* qp, bf16_t* kp,
                                             bf16_t* vh){
  bf16_t* Cp = (seg == 0) ? qp : (seg == 1) ? kp : vh;
  float scale = (seg == 0) ? 0.125f * LOG2E : 1.0f;  // fold softmax scale + log2e into Q
  #pragma unroll
  for (int ti = 0; ti < 4; ti++){
    #pragma unroll
    for (int tj = 0; tj < 4; tj++){
      int col = (n0g + wn + tj*16 + l16) & 1023;
      float bvv = bias[col];
      #pragma unroll
      for (int r = 0; r < 4; r++){
        int row = m0 + wm + ti*16 + lq*4 + r;
        Cp[(size_t)row * 1024 + col] = (bf16_t)((acc[ti][tj][r] + bvv) * scale);
      }
    }
  }
}

// ---------------- fused QKV GEMM, all-bf16 (path A): BK=64, XCD-localized A ----------------
// Grid (32 m-tiles, 24 n-tiles), m fastest: all 8 n-blocks of one (m,seg) share
// id%8 -> same XCD -> A-strip fetched once per XCD. Inner structure = gemm_out's
// proven BK=64 form (4+4 loads/thread, kk half-split reads), 16 barrier-pairs vs 32.
__global__ __launch_bounds__(256) void gemm_qkv_bf(const bf16_t* __restrict__ qkvin,
                                                   const bf16_t* __restrict__ Wcat,
                                                   const float* __restrict__ bq,
                                                   const float* __restrict__ bk,
                                                   const float* __restrict__ bv,
                                                   bf16_t* __restrict__ qp,
                                                   bf16_t* __restrict__ kp,
                                                   bf16_t* __restrict__ vh){
  const int K = 1024;
  __shared__ __align__(16) bf16_t As[128*64];
  __shared__ __align__(16) bf16_t Bs[128*64];
  int tid = threadIdx.x, wave = tid >> 6, lane = tid & 63;
  int l16 = lane & 15, lq = lane >> 4;
  int m0  = blockIdx.x * 128;
  int n0g = blockIdx.y * 128;
  int seg = n0g >> 10;
  const bf16_t* A   = qkvin + (size_t)seg * 4194304;
  const float* bias = (seg == 0) ? bq : (seg == 1) ? bk : bv;
  int wm = (wave >> 1) * 64, wn = (wave & 1) * 64;
  f32x4 acc[4][4] = {};
  for (int kt = 0; kt < K; kt += 64){
    __syncthreads();
    #pragma unroll
    for (int i = 0; i < 4; i++){
      int u = tid + 256*i;
      int r = u >> 3, cpos = u & 7, cg = cpos ^ (r & 7);
      int ldsoff = (wave*64 + 256*i) * 16;
      load_lds_16B(&A[(size_t)(m0 + r) * K + kt + cg*8], (char*)As + ldsoff);
      load_lds_16B(&Wcat[(size_t)(n0g + r) * K + kt + cg*8], (char*)Bs + ldsoff);
    }
    __syncthreads();
    #pragma unroll
    for (int kk = 0; kk < 2; kk++){
      bf16x8 af[4], bfr[4];
      #pragma unroll
      for (int t = 0; t < 4; t++){
        int row = wm + t*16 + l16, cpos = (kk*4 + lq) ^ (l16 & 7);
        af[t] = *reinterpret_cast<bf16x8*>(&As[row*64 + cpos*8]);
      }
      #pragma unroll
      for (int t = 0; t < 4; t++){
        int row = wn + t*16 + l16, cpos = (kk*4 + lq) ^ (l16 & 7);
        bfr[t] = *reinterpret_cast<bf16x8*>(&Bs[row*64 + cpos*8]);
      }
      #pragma unroll
      for (int ti = 0; ti < 4; ti++)
        #pragma unroll
        for (int tj = 0; tj < 4; tj++)
          acc[ti][tj] = __builtin_amdgcn_mfma_f32_16x16x32_bf16(af[ti], bfr[tj], acc[ti][tj], 0, 0, 0);
    }
  }
  qkv_epilogue(acc, seg, n0g, m0, wm, wn, l16, lq, bias, qp, kp, vh);
}

// ---------------- fused QKV GEMM, fp32-A fused-cvt (path B fallback, grid (24,32)) ----------------
__global__ __launch_bounds__(256) void gemm_qkv_f32(const float* __restrict__ qi,
                                                    const float* __restrict__ ki,
                                                    const float* __restrict__ vi,
                                                    const bf16_t* __restrict__ Wcat,
                                                    const float* __restrict__ bq,
                                                    const float* __restrict__ bk,
                                                    const float* __restrict__ bv,
                                                    bf16_t* __restrict__ qp,
                                                    bf16_t* __restrict__ kp,
                                                    bf16_t* __restrict__ vh){
  const int K = 1024;
  __shared__ __align__(16) float  Asf[128*32];
  __shared__ __align__(16) bf16_t Bs[128*32];
  int tid = threadIdx.x, wave = tid >> 6, lane = tid & 63;
  int l16 = lane & 15, lq = lane >> 4;
  int n0g = blockIdx.x * 128;
  int seg = n0g >> 10;
  const float* A    = (seg == 0) ? qi : (seg == 1) ? ki : vi;
  const float* bias = (seg == 0) ? bq : (seg == 1) ? bk : bv;
  int m0 = blockIdx.y * 128;
  int wm = (wave >> 1) * 64, wn = (wave & 1) * 64;
  int cposR = lq ^ ((l16 >> 2) & 3);
  int ca0 = (2*lq)     ^ (l16 & 7);
  int ca1 = (2*lq + 1) ^ (l16 & 7);
  f32x4 acc[4][4] = {};
  for (int kt = 0; kt < K; kt += 32){
    __syncthreads();
    #pragma unroll
    for (int i = 0; i < 4; i++){
      int u = tid + 256*i;
      int r = u >> 3, cpos = u & 7, cg = cpos ^ (r & 7);
      load_lds_16B(&A[(size_t)(m0 + r) * K + kt + cg*4], (char*)Asf + (wave*64 + 256*i)*16);
    }
    #pragma unroll
    for (int i = 0; i < 2; i++){
      int u = tid + 256*i;
      int r = u >> 2, cpos = u & 3, cg = cpos ^ ((r >> 2) & 3);
      load_lds_16B(&Wcat[(size_t)(n0g + r) * K + kt + cg*8], (char*)Bs + (wave*64 + 256*i)*16);
    }
    __syncthreads();
    bf16x8 af[4], bfr[4];
    #pragma unroll
    for (int t = 0; t < 4; t++){
      int row = wm + t*16 + l16;
      f32x4 x0 = *reinterpret_cast<f32x4*>(&Asf[row*32 + ca0*4]);
      f32x4 x1 = *reinterpret_cast<f32x4*>(&Asf[row*32 + ca1*4]);
      bf16x8 a;
      a[0] = (bf16_t)x0[0]; a[1] = (bf16_t)x0[1]; a[2] = (bf16_t)x0[2]; a[3] = (bf16_t)x0[3];
      a[4] = (bf16_t)x1[0]; a[5] = (bf16_t)x1[1]; a[6] = (bf16_t)x1[2]; a[7] = (bf16_t)x1[3];
      af[t] = a;
    }
    #pragma unroll
    for (int t = 0; t < 4; t++) bfr[t] = *reinterpret_cast<bf16x8*>(&Bs[(wn + t*16 + l16)*32 + cposR*8]);
    #pragma unroll
    for (int ti = 0; ti < 4; ti++)
      #pragma unroll
      for (int tj = 0; tj < 4; tj++)
        acc[ti][tj] = __builtin_amdgcn_mfma_f32_16x16x32_bf16(af[ti], bfr[tj], acc[ti][tj], 0, 0, 0);
  }
  qkv_epilogue(acc, seg, n0g, m0, wm, wn, l16, lq, bias, qp, kp, vh);
}

// ---------------- output GEMM: d_out = ctx @ Wot^T + bo; grid (32 m, 16 n), m fastest ----------------
__global__ __launch_bounds__(256) void gemm_out(const bf16_t* __restrict__ A,
                                                const bf16_t* __restrict__ Bt,
                                                const float* __restrict__ bias,
                                                float* __restrict__ C){
  const int K = 1024, N = 1024;
  __shared__ __align__(16) bf16_t As[128*64];
  __shared__ __align__(16) bf16_t Bs[64*64];
  int tid = threadIdx.x, wave = tid >> 6, lane = tid & 63;
  int l16 = lane & 15, lq = lane >> 4;
  int m0 = blockIdx.x * 128, n0 = blockIdx.y * 64;
  int wm = wave * 32;
  f32x4 acc[2][4] = {};
  for (int kt = 0; kt < K; kt += 64){
    __syncthreads();
    #pragma unroll
    for (int i = 0; i < 4; i++){
      int u = tid + 256*i;
      int r = u >> 3, cpos = u & 7, cg = cpos ^ (r & 7);
      load_lds_16B(&A[(size_t)(m0 + r) * K + kt + cg*8], (char*)As + (wave*64 + 256*i)*16);
    }
    #pragma unroll
    for (int i = 0; i < 2; i++){
      int u = tid + 256*i;
      int r = u >> 3, cpos = u & 7, cg = cpos ^ (r & 7);
      load_lds_16B(&Bt[(size_t)(n0 + r) * K + kt + cg*8], (char*)Bs + (wave*64 + 256*i)*16);
    }
    __syncthreads();
    #pragma unroll
    for (int kk = 0; kk < 2; kk++){
      bf16x8 af[2], bfr[4];
      #pragma unroll
      for (int t = 0; t < 2; t++){
        int row = wm + t*16 + l16, cpos = (kk*4 + lq) ^ (l16 & 7);
        af[t] = *reinterpret_cast<bf16x8*>(&As[row*64 + cpos*8]);
      }
      #pragma unroll
      for (int t = 0; t < 4; t++){
        int row = t*16 + l16, cpos = (kk*4 + lq) ^ (l16 & 7);
        bfr[t] = *reinterpret_cast<bf16x8*>(&Bs[row*64 + cpos*8]);
      }
      #pragma unroll
      for (int ti = 0; ti < 2; ti++)
        #pragma unroll
        for (int tj = 0; tj < 4; tj++)
          acc[ti][tj] = __builtin_amdgcn_mfma_f32_16x16x32_bf16(af[ti], bfr[tj], acc[ti][tj], 0, 0, 0);
    }
  }
  #pragma unroll
  for (int ti = 0; ti < 2; ti++){
    #pragma unroll
    for (int tj = 0; tj < 4; tj++){
      int col = n0 + tj*16 + l16;
      float bvv = bias[col];
      #pragma unroll
      for (int r = 0; r < 4; r++){
        int row = m0 + wm + ti*16 + lq*4 + r;
        C[(size_t)row * N + col] = acc[ti][tj][r] + bvv;
      }
    }
  }
}

// ---------------- per-head V transpose: vh[b*2048+s][h*64+d] -> Vt[(b*16+h)*64+d][s] ----------------
__global__ __launch_bounds__(256) void vtrans_kernel(const bf16_t* __restrict__ vh,
                                                     bf16_t* __restrict__ Vt){
  __shared__ bf16_t T[64][72];
  int tid = threadIdx.x;
  int s0 = blockIdx.x * 64, h = blockIdx.y, b = blockIdx.z;
  #pragma unroll
  for (int i = 0; i < 2; i++){
    int u = tid + 256*i;
    int r = u >> 3, c = (u & 7) * 8;
    *reinterpret_cast<uint4*>(&T[r][c]) =
      *reinterpret_cast<const uint4*>(&vh[(size_t)(b*2048 + s0 + r) * 1024 + h*64 + c]);
  }
  __syncthreads();
  #pragma unroll
  for (int i = 0; i < 2; i++){
    int u = tid + 256*i;
    int d = u >> 3, cs = (u & 7) * 8;
    bf16_t t8[8];
    #pragma unroll
    for (int j = 0; j < 8; j++) t8[j] = T[cs + j][d];
    *reinterpret_cast<uint4*>(&Vt[(size_t)((b*16 + h)*64 + d) * 2048 + s0 + cs]) =
      *reinterpret_cast<uint4*>(t8);
  }
}

// ---------------- flash attention v10: v9 body + XCD-localized grid + fused mask scale ----
// Grid (h=16, b=2, qt=16): all 16 qt-blocks of one (b,h) have id%8 == h%8 -> same XCD
// -> K/V slice (512 KB) fetched once per XCD instead of 8x. Mask: raw f32 staged to
// LDS, scaled in-place by -1e12*log2e in the prologue (mask_scale kernel removed).
// Rest = v9: 128q/block, 8 waves (qo,khalf), 4+4 K/V bufs, 2 tiles/barrier depth-2
// prefetch, mask C-init, ones-MFMA row-sums, setprio on MFMA clusters.
__global__ __launch_bounds__(512, 4) void attn_kernel(const bf16_t* __restrict__ qp,
                                                      const bf16_t* __restrict__ kp,
                                                      const bf16_t* __restrict__ vt,
                                                      const float* __restrict__ mask,
                                                      bf16_t* __restrict__ ctx){
  const int S = 2048, D = 1024, HD = 64;
  __shared__ __align__(16) char smem[74240];
  float* Lsum  = (float*)(smem + 73728);   // [128]
  float* Opart = (float*)smem;             // epilogue overlay: 32 KB
  float* Mlw   = (float*)(smem + 65536);   // mask f32 [2048]
  const float* Ml = Mlw;
  int tid = threadIdx.x, wave = tid >> 6, lane = tid & 63;
  int l32 = lane & 31, H = lane >> 5;
  int qo = wave >> 1, khalf = wave & 1;
  int h = blockIdx.x, b = blockIdx.y, qt = blockIdx.z;
  const bf16_t* Qg = qp + (size_t)b*S*D + h*HD;
  const bf16_t* Kg = kp + (size_t)b*S*D + h*HD;
  const bf16_t* Vg = vt + (size_t)(b*16 + h)*HD*S;
  const float*  Mg = mask + (size_t)b*S;

  auto stage = [&](int kt, int bsel){
    char* Kd = smem + bsel*8192;
    char* Vd = smem + 32768 + bsel*8192;
    int r = tid >> 3, c = tid & 7, cg = c ^ (r & 7);
    int ldsoff = wave * 1024;  // wave-uniform base; HW adds lane*16
    load_lds_16B(&Kg[(size_t)(kt + r) * D + cg*8], Kd + ldsoff);
    load_lds_16B(&Vg[(size_t)r * S + kt + cg*8], Vd + ldsoff);
  };

  // Q fragments straight from global: B-operand, lane n=qrow, k=d=16s+8H+j
  int qrow = qt*128 + qo*32 + l32;
  bf16x8 qf[4];
  #pragma unroll
  for (int s = 0; s < 4; s++)
    qf[s] = *reinterpret_cast<const bf16x8*>(&Qg[(size_t)qrow * D + s*16 + 8*H]);

  f32x16 o0 = zero16(), o1 = zero16(), lmm = zero16();
  int krow = khalf*32 + l32;

  pk16 ones;
  ones.h[0].x = 0x3F803F80u; ones.h[0].y = 0x3F803F80u;
  ones.h[1].x = 0x3F803F80u; ones.h[1].y = 0x3F803F80u;

  // prologue: raw mask row (8 KB) + tiles 0,1; then scale mask in LDS
  load_lds_16B(&Mg[(size_t)tid*4], smem + 65536 + wave*1024);
  stage(0, 0);
  stage(64, 1);
  __syncthreads();
  {
    f32x4 mv = *reinterpret_cast<f32x4*>(&Mlw[tid*4]);
    mv *= MBIAS_C;
    *reinterpret_cast<f32x4*>(&Mlw[tid*4]) = mv;
  }
  __syncthreads();

  auto tile_compute = [&](int kt, int cur){
    bf16_t* Ks  = (bf16_t*)(smem + cur*8192);
    bf16_t* Vts = (bf16_t*)(smem + 32768 + cur*8192);
    // mask C-init from LDS (quarter-wave broadcast ds_reads)
    cinit_t ci;
    #pragma unroll
    for (int g = 0; g < 4; g++)
      ci.f4[g] = *reinterpret_cast<const float4*>(&Ml[kt + khalf*32 + 8*g + 4*H]);
    // QK: one 32x32 Sc^T tile, chained over d=64, mask rides in as C operand
    f32x16 sc;
    __builtin_amdgcn_s_setprio(1);
    #pragma unroll
    for (int s = 0; s < 4; s++){
      int cp = (2*s + H) ^ (l32 & 7);  // krow&7 == l32&7
      bf16x8 kf = *reinterpret_cast<bf16x8*>(&Ks[krow*64 + cp*8]);
      if (s == 0) sc = __builtin_amdgcn_mfma_f32_32x32x16_bf16(kf, qf[0], ci.v, 0, 0, 0);
      else        sc = __builtin_amdgcn_mfma_f32_32x32x16_bf16(kf, qf[s], sc, 0, 0, 0);
    }
    __builtin_amdgcn_s_setprio(0);
    // exp; C-layout: lane owns q-col l32; tile-key = khalf*32 + 8g + 4H + r (reg=4g+r)
    pk8 grp[4];
    #pragma unroll
    for (int g = 0; g < 4; g++){
      float p0 = EXP2F(sc[4*g+0]);
      float p1 = EXP2F(sc[4*g+1]);
      float p2 = EXP2F(sc[4*g+2]);
      float p3 = EXP2F(sc[4*g+3]);
      pk8 w;
      w.b4[0] = (bf16_t)p0; w.b4[1] = (bf16_t)p1; w.b4[2] = (bf16_t)p2; w.b4[3] = (bf16_t)p3;
      grp[g] = w;
    }
    // PV with register transpose; window kk covers tile-keys khalf*32 + 16kk + 8H + j
    #pragma unroll
    for (int kk = 0; kk < 2; kk++){
      uint2 ga = grp[2*kk].u2;
      uint2 gb = grp[2*kk+1].u2;
      uint2 send = H ? ga : gb;
      uint2 recv;
      recv.x = (unsigned)__shfl_xor((int)send.x, 32);
      recv.y = (unsigned)__shfl_xor((int)send.y, 32);
      pk16 fr;
      fr.h[0] = H ? recv : ga;
      fr.h[1] = H ? gb : recv;
      int cp = (4*khalf + 2*kk + H) ^ (l32 & 7);
      bf16x8 vf0 = *reinterpret_cast<bf16x8*>(&Vts[l32*64 + cp*8]);
      bf16x8 vf1 = *reinterpret_cast<bf16x8*>(&Vts[(32 + l32)*64 + cp*8]);
      __builtin_amdgcn_s_setprio(1);
      o0  = __builtin_amdgcn_mfma_f32_32x32x16_bf16(fr.b8, vf0, o0, 0, 0, 0);
      o1  = __builtin_amdgcn_mfma_f32_32x32x16_bf16(fr.b8, vf1, o1, 0, 0, 0);
      lmm = __builtin_amdgcn_mfma_f32_32x32x16_bf16(fr.b8, ones.b8, lmm, 0, 0, 0);
      __builtin_amdgcn_s_setprio(0);
    }
  };

  // main loop: 2 tiles per iter, depth-2 prefetch, ONE barrier per iter.
  #pragma unroll 2
  for (int it = 0; it < 16; ++it){
    int kt = it * 128;
    if (it < 15){
      stage(kt + 128, (2*it + 2) & 3);
      stage(kt + 192, (2*it + 3) & 3);
    }
    tile_compute(kt,      (2*it) & 3);
    tile_compute(kt + 64, (2*it + 1) & 3);
    __syncthreads();
  }

  // epilogue: combine k-halves through LDS (overlays K bufs), normalize, store
  if (khalf == 1){
    #pragma unroll
    for (int reg = 0; reg < 16; reg++){
      Opart[qo*2048 + reg*64 + lane]        = o0[reg];
      Opart[qo*2048 + 1024 + reg*64 + lane] = o1[reg];
    }
    if (l32 == 0){
      #pragma unroll
      for (int reg = 0; reg < 16; reg++)
        Lsum[qo*32 + (reg & 3) + 8*(reg >> 2) + 4*H] = lmm[reg];
    }
  }
  __syncthreads();
  if (khalf == 0){
    #pragma unroll
    for (int reg = 0; reg < 16; reg++){
      o0[reg] += Opart[qo*2048 + reg*64 + lane];
      o1[reg] += Opart[qo*2048 + 1024 + reg*64 + lane];
    }
    #pragma unroll
    for (int g = 0; g < 4; g++){
      #pragma unroll
      for (int r = 0; r < 4; r++){
        float lf = lmm[4*g + r] + Lsum[qo*32 + 8*g + 4*H + r];
        float inv = 1.f / lf;
        int grow = qt*128 + qo*32 + 8*g + 4*H + r;
        size_t base = (size_t)(b*S + grow) * D + h*HD;
        ctx[base + l32]      = (bf16_t)(o0[4*g + r] * inv);
        ctx[base + 32 + l32] = (bf16_t)(o1[4*g + r] * inv);
      }
    }
  }
}

extern "C" void kernel_launch(void* const* d_in, const int* in_sizes, int n_in,
                              void* d_out, int out_size, void* d_ws, size_t ws_size,
                              hipStream_t stream){
  const float* q    = (const float*)d_in[0];
  const float* k    = (const float*)d_in[1];
  const float* v    = (const float*)d_in[2];
  const float* mask = (const float*)d_in[3];
  const float* Wq   = (const float*)d_in[4];
  const float* bq   = (const float*)d_in[5];
  const float* Wk   = (const float*)d_in[6];
  const float* bk   = (const float*)d_in[7];
  const float* Wv   = (const float*)d_in[8];
  const float* bv   = (const float*)d_in[9];
  const float* Wo   = (const float*)d_in[10];
  const float* bo   = (const float*)d_in[11];

  char* ws = (char*)d_ws;
  bf16_t* qp    = (bf16_t*)(ws);               // [0, 8 MiB)
  bf16_t* kp    = (bf16_t*)(ws + 8388608);     // [8, 16)
  bf16_t* vh    = (bf16_t*)(ws + 16777216);    // [16, 24)
  bf16_t* Wcat  = (bf16_t*)(ws + 25165824);    // [24, 30)
  bf16_t* Wot   = (bf16_t*)(ws + 31457280);    // [30, 32)
  bf16_t* Vt    = (bf16_t*)(ws + 33554432);    // [32, 40)
  bf16_t* ctx   = (bf16_t*)(ws + 41943040);    // [40, 48)
  bf16_t* qkvin = (bf16_t*)(ws + 33554432);    // [32, 56) path A only; dead before Vt/ctx live

  wtrans4_kernel<<<dim3(32,32,4), dim3(32,8), 0, stream>>>(Wq, Wk, Wv, Wo, Wcat, Wot);
  if (ws_size >= 58720256){
    cast3_kernel<<<dim3(4096,3), 256, 0, stream>>>(q, k, v, qkvin);
    gemm_qkv_bf<<<dim3(32,24), 256, 0, stream>>>(qkvin, Wcat, bq, bk, bv, qp, kp, vh);
  } else {
    gemm_qkv_f32<<<dim3(24,32), 256, 0, stream>>>(q, k, v, Wcat, bq, bk, bv, qp, kp, vh);
  }
  vtrans_kernel<<<dim3(32,16,2), 256, 0, stream>>>(vh, Vt);
  attn_kernel<<<dim3(16,2,16), 512, 0, stream>>>(qp, kp, Vt, mask, ctx);
  gemm_out<<<dim3(32,16), 256, 0, stream>>>(ctx, Wot, bo, (float*)d_out);
}

// Round 8
// 224.633 us; speedup vs baseline: 1.0504x; 1.0319x over previous
//
#include <hip/hip_runtime.h>
#include <math.h>

typedef __bf16 bf16_t;
typedef __bf16 bf16x8 __attribute__((ext_vector_type(8)));
typedef __bf16 bf16x4v __attribute__((ext_vector_type(4)));
typedef float f32x4 __attribute__((ext_vector_type(4)));
typedef float f32x16 __attribute__((ext_vector_type(16)));

#define LOG2E 1.4426950408889634f
#define MBIAS_C (-1e12f * LOG2E)

#if __has_builtin(__builtin_amdgcn_exp2f)
#define EXP2F(x) __builtin_amdgcn_exp2f(x)
#else
#define EXP2F(x) exp2f(x)
#endif

typedef __attribute__((address_space(1))) const unsigned int g_u32;
typedef __attribute__((address_space(3))) unsigned int l_u32;
__device__ __forceinline__ void load_lds_16B(const void* g, void* l){
  __builtin_amdgcn_global_load_lds((g_u32*)g, (l_u32*)l, 16, 0, 0);
}

__device__ __forceinline__ f32x16 zero16(){
  f32x16 z;
  #pragma unroll
  for (int i = 0; i < 16; i++) z[i] = 0.f;
  return z;
}

typedef union { bf16x4v b4; uint2 u2; } pk8;
typedef union { uint2 h[2]; bf16x8 b8; } pk16;
typedef union { float4 f4[4]; f32x16 v; } cinit_t;

// ---------------- prep: weight transpose+cast (4x1024 blocks) + q/k/v cast (cast_blocks) ----
// Branch is block-uniform (whole block takes one path) so the weight-path __syncthreads
// is safe. Merging saves a kernel launch and overlaps the BW-bound cast with the
// transpose's LDS work.
__global__ __launch_bounds__(256) void prep_kernel(const float* __restrict__ q,
                                                   const float* __restrict__ k,
                                                   const float* __restrict__ v,
                                                   const float* __restrict__ Wq,
                                                   const float* __restrict__ Wk,
                                                   const float* __restrict__ Wv,
                                                   const float* __restrict__ Wo,
                                                   bf16_t* __restrict__ qkvin,
                                                   bf16_t* __restrict__ Wcat,
                                                   bf16_t* __restrict__ Wot,
                                                   int cast_blocks){
  __shared__ float T[32][33];
  int id = blockIdx.x, tid = threadIdx.x;
  if (id < cast_blocks){
    // cast q,k,v fp32 -> bf16 planes (4096 blocks per plane)
    int z = id >> 12;
    int i = (id & 4095) * 256 + tid;
    const float* x = (z == 0) ? q : (z == 1) ? k : v;
    float4 f = reinterpret_cast<const float4*>(x)[i];
    bf16x4v w;
    w[0] = (bf16_t)f.x; w[1] = (bf16_t)f.y; w[2] = (bf16_t)f.z; w[3] = (bf16_t)f.w;
    reinterpret_cast<bf16x4v*>(qkvin + (size_t)z * 4194304)[i] = w;
  } else {
    // weight transpose+cast: 1024 32x32 tiles per weight
    int wid = id - cast_blocks;
    int z = wid >> 10, t = wid & 1023;
    int k0 = (t >> 5) * 32, n0 = (t & 31) * 32;
    int x = tid & 31, y = tid >> 5;  // (32,8) layout
    const float* W = (z == 0) ? Wq : (z == 1) ? Wk : (z == 2) ? Wv : Wo;
    bf16_t* dst = (z < 3) ? (Wcat + (size_t)z * 1024 * 1024) : Wot;
    #pragma unroll
    for (int i = 0; i < 4; i++) T[y + 8*i][x] = W[(size_t)(k0 + y + 8*i) * 1024 + n0 + x];
    __syncthreads();
    #pragma unroll
    for (int i = 0; i < 4; i++) dst[(size_t)(n0 + y + 8*i) * 1024 + k0 + x] = (bf16_t)T[x][y + 8*i];
  }
}

// ---------------- shared epilogue for QKV GEMMs: write q/k/v planes ----------------
__device__ __forceinline__ void qkv_epilogue(f32x4 (&acc)[4][4], int seg, int n0g, int m0,
                                             int wm, int wn, int l16, int lq,
                                             const float* bias, bf16_t* qp, bf16_t* kp,
                                             bf16_t* vh){
  bf16_t* Cp = (seg == 0) ? qp : (seg == 1) ? kp : vh;
  float scale = (seg == 0) ? 0.125f * LOG2E : 1.0f;  // fold softmax scale + log2e into Q
  #pragma unroll
  for (int ti = 0; ti < 4; ti++){
    #pragma unroll
    for (int tj = 0; tj < 4; tj++){
      int col = (n0g + wn + tj*16 + l16) & 1023;
      float bvv = bias[col];
      #pragma unroll
      for (int r = 0; r < 4; r++){
        int row = m0 + wm + ti*16 + lq*4 + r;
        Cp[(size_t)row * 1024 + col] = (bf16_t)((acc[ti][tj][r] + bvv) * scale);
      }
    }
  }
}

// ---------------- fused QKV GEMM, all-bf16 (path A): BK=32 dbuf, prefetch-before-compute ----
// Per iter: {stage(t+1) -> buf^1; compute(t) on buf; __syncthreads}. One barrier/iter;
// stage latency hides under the 16-MFMA compute (attn-v7-proven loop form; dbuf
// indexing correctness-verified in R3). Grid (32 m, 24 n) m-fastest for XCD A-locality.
__global__ __launch_bounds__(256) void gemm_qkv_bf(const bf16_t* __restrict__ qkvin,
                                                   const bf16_t* __restrict__ Wcat,
                                                   const float* __restrict__ bq,
                                                   const float* __restrict__ bk,
                                                   const float* __restrict__ bv,
                                                   bf16_t* __restrict__ qp,
                                                   bf16_t* __restrict__ kp,
                                                   bf16_t* __restrict__ vh){
  const int K = 1024;
  __shared__ __align__(16) bf16_t As[2][128*32];
  __shared__ __align__(16) bf16_t Bs[2][128*32];
  int tid = threadIdx.x, wave = tid >> 6, lane = tid & 63;
  int l16 = lane & 15, lq = lane >> 4;
  int m0  = blockIdx.x * 128;
  int n0g = blockIdx.y * 128;
  int seg = n0g >> 10;
  const bf16_t* A   = qkvin + (size_t)seg * 4194304;
  const float* bias = (seg == 0) ? bq : (seg == 1) ? bk : bv;
  int wm = (wave >> 1) * 64, wn = (wave & 1) * 64;
  int cposR = lq ^ ((l16 >> 2) & 3);
  f32x4 acc[4][4] = {};

  auto stage = [&](int kt, int bsel){
    #pragma unroll
    for (int i = 0; i < 2; i++){
      int u = tid + 256*i;
      int r = u >> 2, cpos = u & 3, cg = cpos ^ ((r >> 2) & 3);
      int ldsoff = (wave*64 + 256*i) * 16;
      load_lds_16B(&A[(size_t)(m0 + r) * K + kt + cg*8], (char*)As[bsel] + ldsoff);
      load_lds_16B(&Wcat[(size_t)(n0g + r) * K + kt + cg*8], (char*)Bs[bsel] + ldsoff);
    }
  };
  auto compute = [&](int cur){
    bf16x8 af[4], bfr[4];
    #pragma unroll
    for (int t = 0; t < 4; t++) af[t]  = *reinterpret_cast<bf16x8*>(&As[cur][(wm + t*16 + l16)*32 + cposR*8]);
    #pragma unroll
    for (int t = 0; t < 4; t++) bfr[t] = *reinterpret_cast<bf16x8*>(&Bs[cur][(wn + t*16 + l16)*32 + cposR*8]);
    #pragma unroll
    for (int ti = 0; ti < 4; ti++)
      #pragma unroll
      for (int tj = 0; tj < 4; tj++)
        acc[ti][tj] = __builtin_amdgcn_mfma_f32_16x16x32_bf16(af[ti], bfr[tj], acc[ti][tj], 0, 0, 0);
  };

  stage(0, 0);
  __syncthreads();
  #pragma unroll 1
  for (int it = 0; it < 32; ++it){
    if (it < 31) stage((it + 1) * 32, (it + 1) & 1);
    compute(it & 1);
    __syncthreads();
  }
  qkv_epilogue(acc, seg, n0g, m0, wm, wn, l16, lq, bias, qp, kp, vh);
}

// ---------------- fused QKV GEMM, fp32-A fused-cvt (path B fallback, grid (24,32)) ----------------
__global__ __launch_bounds__(256) void gemm_qkv_f32(const float* __restrict__ qi,
                                                    const float* __restrict__ ki,
                                                    const float* __restrict__ vi,
                                                    const bf16_t* __restrict__ Wcat,
                                                    const float* __restrict__ bq,
                                                    const float* __restrict__ bk,
                                                    const float* __restrict__ bv,
                                                    bf16_t* __restrict__ qp,
                                                    bf16_t* __restrict__ kp,
                                                    bf16_t* __restrict__ vh){
  const int K = 1024;
  __shared__ __align__(16) float  Asf[128*32];
  __shared__ __align__(16) bf16_t Bs[128*32];
  int tid = threadIdx.x, wave = tid >> 6, lane = tid & 63;
  int l16 = lane & 15, lq = lane >> 4;
  int n0g = blockIdx.x * 128;
  int seg = n0g >> 10;
  const float* A    = (seg == 0) ? qi : (seg == 1) ? ki : vi;
  const float* bias = (seg == 0) ? bq : (seg == 1) ? bk : bv;
  int m0 = blockIdx.y * 128;
  int wm = (wave >> 1) * 64, wn = (wave & 1) * 64;
  int cposR = lq ^ ((l16 >> 2) & 3);
  int ca0 = (2*lq)     ^ (l16 & 7);
  int ca1 = (2*lq + 1) ^ (l16 & 7);
  f32x4 acc[4][4] = {};
  for (int kt = 0; kt < K; kt += 32){
    __syncthreads();
    #pragma unroll
    for (int i = 0; i < 4; i++){
      int u = tid + 256*i;
      int r = u >> 3, cpos = u & 7, cg = cpos ^ (r & 7);
      load_lds_16B(&A[(size_t)(m0 + r) * K + kt + cg*4], (char*)Asf + (wave*64 + 256*i)*16);
    }
    #pragma unroll
    for (int i = 0; i < 2; i++){
      int u = tid + 256*i;
      int r = u >> 2, cpos = u & 3, cg = cpos ^ ((r >> 2) & 3);
      load_lds_16B(&Wcat[(size_t)(n0g + r) * K + kt + cg*8], (char*)Bs + (wave*64 + 256*i)*16);
    }
    __syncthreads();
    bf16x8 af[4], bfr[4];
    #pragma unroll
    for (int t = 0; t < 4; t++){
      int row = wm + t*16 + l16;
      f32x4 x0 = *reinterpret_cast<f32x4*>(&Asf[row*32 + ca0*4]);
      f32x4 x1 = *reinterpret_cast<f32x4*>(&Asf[row*32 + ca1*4]);
      bf16x8 a;
      a[0] = (bf16_t)x0[0]; a[1] = (bf16_t)x0[1]; a[2] = (bf16_t)x0[2]; a[3] = (bf16_t)x0[3];
      a[4] = (bf16_t)x1[0]; a[5] = (bf16_t)x1[1]; a[6] = (bf16_t)x1[2]; a[7] = (bf16_t)x1[3];
      af[t] = a;
    }
    #pragma unroll
    for (int t = 0; t < 4; t++) bfr[t] = *reinterpret_cast<bf16x8*>(&Bs[(wn + t*16 + l16)*32 + cposR*8]);
    #pragma unroll
    for (int ti = 0; ti < 4; ti++)
      #pragma unroll
      for (int tj = 0; tj < 4; tj++)
        acc[ti][tj] = __builtin_amdgcn_mfma_f32_16x16x32_bf16(af[ti], bfr[tj], acc[ti][tj], 0, 0, 0);
  }
  qkv_epilogue(acc, seg, n0g, m0, wm, wn, l16, lq, bias, qp, kp, vh);
}

// ---------------- output GEMM: BK=64 dbuf prefetch; grid (32 m, 16 n) ----------------
__global__ __launch_bounds__(256) void gemm_out(const bf16_t* __restrict__ A,
                                                const bf16_t* __restrict__ Bt,
                                                const float* __restrict__ bias,
                                                float* __restrict__ C){
  const int K = 1024, N = 1024;
  __shared__ __align__(16) bf16_t As[2][128*64];
  __shared__ __align__(16) bf16_t Bs[2][64*64];
  int tid = threadIdx.x, wave = tid >> 6, lane = tid & 63;
  int l16 = lane & 15, lq = lane >> 4;
  int m0 = blockIdx.x * 128, n0 = blockIdx.y * 64;
  int wm = wave * 32;
  f32x4 acc[2][4] = {};

  auto stage = [&](int kt, int bsel){
    #pragma unroll
    for (int i = 0; i < 4; i++){
      int u = tid + 256*i;
      int r = u >> 3, cpos = u & 7, cg = cpos ^ (r & 7);
      load_lds_16B(&A[(size_t)(m0 + r) * K + kt + cg*8], (char*)As[bsel] + (wave*64 + 256*i)*16);
    }
    #pragma unroll
    for (int i = 0; i < 2; i++){
      int u = tid + 256*i;
      int r = u >> 3, cpos = u & 7, cg = cpos ^ (r & 7);
      load_lds_16B(&Bt[(size_t)(n0 + r) * K + kt + cg*8], (char*)Bs[bsel] + (wave*64 + 256*i)*16);
    }
  };
  auto compute = [&](int cur){
    #pragma unroll
    for (int kk = 0; kk < 2; kk++){
      bf16x8 af[2], bfr[4];
      #pragma unroll
      for (int t = 0; t < 2; t++){
        int row = wm + t*16 + l16, cpos = (kk*4 + lq) ^ (l16 & 7);
        af[t] = *reinterpret_cast<bf16x8*>(&As[cur][row*64 + cpos*8]);
      }
      #pragma unroll
      for (int t = 0; t < 4; t++){
        int row = t*16 + l16, cpos = (kk*4 + lq) ^ (l16 & 7);
        bfr[t] = *reinterpret_cast<bf16x8*>(&Bs[cur][row*64 + cpos*8]);
      }
      #pragma unroll
      for (int ti = 0; ti < 2; ti++)
        #pragma unroll
        for (int tj = 0; tj < 4; tj++)
          acc[ti][tj] = __builtin_amdgcn_mfma_f32_16x16x32_bf16(af[ti], bfr[tj], acc[ti][tj], 0, 0, 0);
    }
  };

  stage(0, 0);
  __syncthreads();
  #pragma unroll 1
  for (int it = 0; it < 16; ++it){
    if (it < 15) stage((it + 1) * 64, (it + 1) & 1);
    compute(it & 1);
    __syncthreads();
  }

  #pragma unroll
  for (int ti = 0; ti < 2; ti++){
    #pragma unroll
    for (int tj = 0; tj < 4; tj++){
      int col = n0 + tj*16 + l16;
      float bvv = bias[col];
      #pragma unroll
      for (int r = 0; r < 4; r++){
        int row = m0 + wm + ti*16 + lq*4 + r;
        C[(size_t)row * N + col] = acc[ti][tj][r] + bvv;
      }
    }
  }
}

// ---------------- per-head V transpose: vh[b*2048+s][h*64+d] -> Vt[(b*16+h)*64+d][s] ----------------
__global__ __launch_bounds__(256) void vtrans_kernel(const bf16_t* __restrict__ vh,
                                                     bf16_t* __restrict__ Vt){
  __shared__ bf16_t T[64][72];
  int tid = threadIdx.x;
  int s0 = blockIdx.x * 64, h = blockIdx.y, b = blockIdx.z;
  #pragma unroll
  for (int i = 0; i < 2; i++){
    int u = tid + 256*i;
    int r = u >> 3, c = (u & 7) * 8;
    *reinterpret_cast<uint4*>(&T[r][c]) =
      *reinterpret_cast<const uint4*>(&vh[(size_t)(b*2048 + s0 + r) * 1024 + h*64 + c]);
  }
  __syncthreads();
  #pragma unroll
  for (int i = 0; i < 2; i++){
    int u = tid + 256*i;
    int d = u >> 3, cs = (u & 7) * 8;
    bf16_t t8[8];
    #pragma unroll
    for (int j = 0; j < 8; j++) t8[j] = T[cs + j][d];
    *reinterpret_cast<uint4*>(&Vt[(size_t)((b*16 + h)*64 + d) * 2048 + s0 + cs]) =
      *reinterpret_cast<uint4*>(t8);
  }
}

// ---------------- flash attention v10 (unchanged from R7) ----------------
__global__ __launch_bounds__(512, 4) void attn_kernel(const bf16_t* __restrict__ qp,
                                                      const bf16_t* __restrict__ kp,
                                                      const bf16_t* __restrict__ vt,
                                                      const float* __restrict__ mask,
                                                      bf16_t* __restrict__ ctx){
  const int S = 2048, D = 1024, HD = 64;
  __shared__ __align__(16) char smem[74240];
  float* Lsum  = (float*)(smem + 73728);   // [128]
  float* Opart = (float*)smem;             // epilogue overlay: 32 KB
  float* Mlw   = (float*)(smem + 65536);   // mask f32 [2048]
  const float* Ml = Mlw;
  int tid = threadIdx.x, wave = tid >> 6, lane = tid & 63;
  int l32 = lane & 31, H = lane >> 5;
  int qo = wave >> 1, khalf = wave & 1;
  int h = blockIdx.x, b = blockIdx.y, qt = blockIdx.z;
  const bf16_t* Qg = qp + (size_t)b*S*D + h*HD;
  const bf16_t* Kg = kp + (size_t)b*S*D + h*HD;
  const bf16_t* Vg = vt + (size_t)(b*16 + h)*HD*S;
  const float*  Mg = mask + (size_t)b*S;

  auto stage = [&](int kt, int bsel){
    char* Kd = smem + bsel*8192;
    char* Vd = smem + 32768 + bsel*8192;
    int r = tid >> 3, c = tid & 7, cg = c ^ (r & 7);
    int ldsoff = wave * 1024;  // wave-uniform base; HW adds lane*16
    load_lds_16B(&Kg[(size_t)(kt + r) * D + cg*8], Kd + ldsoff);
    load_lds_16B(&Vg[(size_t)r * S + kt + cg*8], Vd + ldsoff);
  };

  int qrow = qt*128 + qo*32 + l32;
  bf16x8 qf[4];
  #pragma unroll
  for (int s = 0; s < 4; s++)
    qf[s] = *reinterpret_cast<const bf16x8*>(&Qg[(size_t)qrow * D + s*16 + 8*H]);

  f32x16 o0 = zero16(), o1 = zero16(), lmm = zero16();
  int krow = khalf*32 + l32;

  pk16 ones;
  ones.h[0].x = 0x3F803F80u; ones.h[0].y = 0x3F803F80u;
  ones.h[1].x = 0x3F803F80u; ones.h[1].y = 0x3F803F80u;

  // prologue: raw mask row (8 KB) + tiles 0,1; then scale mask in LDS
  load_lds_16B(&Mg[(size_t)tid*4], smem + 65536 + wave*1024);
  stage(0, 0);
  stage(64, 1);
  __syncthreads();
  {
    f32x4 mv = *reinterpret_cast<f32x4*>(&Mlw[tid*4]);
    mv *= MBIAS_C;
    *reinterpret_cast<f32x4*>(&Mlw[tid*4]) = mv;
  }
  __syncthreads();

  auto tile_compute = [&](int kt, int cur){
    bf16_t* Ks  = (bf16_t*)(smem + cur*8192);
    bf16_t* Vts = (bf16_t*)(smem + 32768 + cur*8192);
    cinit_t ci;
    #pragma unroll
    for (int g = 0; g < 4; g++)
      ci.f4[g] = *reinterpret_cast<const float4*>(&Ml[kt + khalf*32 + 8*g + 4*H]);
    f32x16 sc;
    __builtin_amdgcn_s_setprio(1);
    #pragma unroll
    for (int s = 0; s < 4; s++){
      int cp = (2*s + H) ^ (l32 & 7);  // krow&7 == l32&7
      bf16x8 kf = *reinterpret_cast<bf16x8*>(&Ks[krow*64 + cp*8]);
      if (s == 0) sc = __builtin_amdgcn_mfma_f32_32x32x16_bf16(kf, qf[0], ci.v, 0, 0, 0);
      else        sc = __builtin_amdgcn_mfma_f32_32x32x16_bf16(kf, qf[s], sc, 0, 0, 0);
    }
    __builtin_amdgcn_s_setprio(0);
    pk8 grp[4];
    #pragma unroll
    for (int g = 0; g < 4; g++){
      float p0 = EXP2F(sc[4*g+0]);
      float p1 = EXP2F(sc[4*g+1]);
      float p2 = EXP2F(sc[4*g+2]);
      float p3 = EXP2F(sc[4*g+3]);
      pk8 w;
      w.b4[0] = (bf16_t)p0; w.b4[1] = (bf16_t)p1; w.b4[2] = (bf16_t)p2; w.b4[3] = (bf16_t)p3;
      grp[g] = w;
    }
    #pragma unroll
    for (int kk = 0; kk < 2; kk++){
      uint2 ga = grp[2*kk].u2;
      uint2 gb = grp[2*kk+1].u2;
      uint2 send = H ? ga : gb;
      uint2 recv;
      recv.x = (unsigned)__shfl_xor((int)send.x, 32);
      recv.y = (unsigned)__shfl_xor((int)send.y, 32);
      pk16 fr;
      fr.h[0] = H ? recv : ga;
      fr.h[1] = H ? gb : recv;
      int cp = (4*khalf + 2*kk + H) ^ (l32 & 7);
      bf16x8 vf0 = *reinterpret_cast<bf16x8*>(&Vts[l32*64 + cp*8]);
      bf16x8 vf1 = *reinterpret_cast<bf16x8*>(&Vts[(32 + l32)*64 + cp*8]);
      __builtin_amdgcn_s_setprio(1);
      o0  = __builtin_amdgcn_mfma_f32_32x32x16_bf16(fr.b8, vf0, o0, 0, 0, 0);
      o1  = __builtin_amdgcn_mfma_f32_32x32x16_bf16(fr.b8, vf1, o1, 0, 0, 0);
      lmm = __builtin_amdgcn_mfma_f32_32x32x16_bf16(fr.b8, ones.b8, lmm, 0, 0, 0);
      __builtin_amdgcn_s_setprio(0);
    }
  };

  #pragma unroll 2
  for (int it = 0; it < 16; ++it){
    int kt = it * 128;
    if (it < 15){
      stage(kt + 128, (2*it + 2) & 3);
      stage(kt + 192, (2*it + 3) & 3);
    }
    tile_compute(kt,      (2*it) & 3);
    tile_compute(kt + 64, (2*it + 1) & 3);
    __syncthreads();
  }

  if (khalf == 1){
    #pragma unroll
    for (int reg = 0; reg < 16; reg++){
      Opart[qo*2048 + reg*64 + lane]        = o0[reg];
      Opart[qo*2048 + 1024 + reg*64 + lane] = o1[reg];
    }
    if (l32 == 0){
      #pragma unroll
      for (int reg = 0; reg < 16; reg++)
        Lsum[qo*32 + (reg & 3) + 8*(reg >> 2) + 4*H] = lmm[reg];
    }
  }
  __syncthreads();
  if (khalf == 0){
    #pragma unroll
    for (int reg = 0; reg < 16; reg++){
      o0[reg] += Opart[qo*2048 + reg*64 + lane];
      o1[reg] += Opart[qo*2048 + 1024 + reg*64 + lane];
    }
    #pragma unroll
    for (int g = 0; g < 4; g++){
      #pragma unroll
      for (int r = 0; r < 4; r++){
        float lf = lmm[4*g + r] + Lsum[qo*32 + 8*g + 4*H + r];
        float inv = 1.f / lf;
        int grow = qt*128 + qo*32 + 8*g + 4*H + r;
        size_t base = (size_t)(b*S + grow) * D + h*HD;
        ctx[base + l32]      = (bf16_t)(o0[4*g + r] * inv);
        ctx[base + 32 + l32] = (bf16_t)(o1[4*g + r] * inv);
      }
    }
  }
}

extern "C" void kernel_launch(void* const* d_in, const int* in_sizes, int n_in,
                              void* d_out, int out_size, void* d_ws, size_t ws_size,
                              hipStream_t stream){
  const float* q    = (const float*)d_in[0];
  const float* k    = (const float*)d_in[1];
  const float* v    = (const float*)d_in[2];
  const float* mask = (const float*)d_in[3];
  const float* Wq   = (const float*)d_in[4];
  const float* bq   = (const float*)d_in[5];
  const float* Wk   = (const float*)d_in[6];
  const float* bk   = (const float*)d_in[7];
  const float* Wv   = (const float*)d_in[8];
  const float* bv   = (const float*)d_in[9];
  const float* Wo   = (const float*)d_in[10];
  const float* bo   = (const float*)d_in[11];

  char* ws = (char*)d_ws;
  bf16_t* qp    = (bf16_t*)(ws);               // [0, 8 MiB)
  bf16_t* kp    = (bf16_t*)(ws + 8388608);     // [8, 16)
  bf16_t* vh    = (bf16_t*)(ws + 16777216);    // [16, 24)
  bf16_t* Wcat  = (bf16_t*)(ws + 25165824);    // [24, 30)
  bf16_t* Wot   = (bf16_t*)(ws + 31457280);    // [30, 32)
  bf16_t* Vt    = (bf16_t*)(ws + 33554432);    // [32, 40)
  bf16_t* ctx   = (bf16_t*)(ws + 41943040);    // [40, 48)
  bf16_t* qkvin = (bf16_t*)(ws + 33554432);    // [32, 56) path A only; dead before Vt/ctx live

  if (ws_size >= 58720256){
    prep_kernel<<<dim3(16384), 256, 0, stream>>>(q, k, v, Wq, Wk, Wv, Wo, qkvin, Wcat, Wot, 12288);
    gemm_qkv_bf<<<dim3(32,24), 256, 0, stream>>>(qkvin, Wcat, bq, bk, bv, qp, kp, vh);
  } else {
    prep_kernel<<<dim3(4096), 256, 0, stream>>>(q, k, v, Wq, Wk, Wv, Wo, qkvin, Wcat, Wot, 0);
    gemm_qkv_f32<<<dim3(24,32), 256, 0, stream>>>(q, k, v, Wcat, bq, bk, bv, qp, kp, vh);
  }
  vtrans_kernel<<<dim3(32,16,2), 256, 0, stream>>>(vh, Vt);
  attn_kernel<<<dim3(16,2,16), 512, 0, stream>>>(qp, kp, Vt, mask, ctx);
  gemm_out<<<dim3(32,16), 256, 0, stream>>>(ctx, Wot, bo, (float*)d_out);
}

// Round 9
// 218.444 us; speedup vs baseline: 1.0802x; 1.0283x over previous
//
#include <hip/hip_runtime.h>
#include <math.h>

typedef __bf16 bf16_t;
typedef __bf16 bf16x8 __attribute__((ext_vector_type(8)));
typedef __bf16 bf16x4v __attribute__((ext_vector_type(4)));
typedef float f32x4 __attribute__((ext_vector_type(4)));
typedef float f32x16 __attribute__((ext_vector_type(16)));

#define LOG2E 1.4426950408889634f
#define MBIAS_C (-1e12f * LOG2E)

#if __has_builtin(__builtin_amdgcn_exp2f)
#define EXP2F(x) __builtin_amdgcn_exp2f(x)
#else
#define EXP2F(x) exp2f(x)
#endif

typedef __attribute__((address_space(1))) const unsigned int g_u32;
typedef __attribute__((address_space(3))) unsigned int l_u32;
__device__ __forceinline__ void load_lds_16B(const void* g, void* l){
  __builtin_amdgcn_global_load_lds((g_u32*)g, (l_u32*)l, 16, 0, 0);
}

__device__ __forceinline__ f32x16 zero16(){
  f32x16 z;
  #pragma unroll
  for (int i = 0; i < 16; i++) z[i] = 0.f;
  return z;
}

typedef union { bf16x4v b4; uint2 u2; } pk8;
typedef union { uint2 h[2]; bf16x8 b8; } pk16;
typedef union { float4 f4[4]; f32x16 v; } cinit_t;

// ---------------- prep: weight transpose+cast (4x1024 blocks) + q/k/v cast (cast_blocks) ----
__global__ __launch_bounds__(256) void prep_kernel(const float* __restrict__ q,
                                                   const float* __restrict__ k,
                                                   const float* __restrict__ v,
                                                   const float* __restrict__ Wq,
                                                   const float* __restrict__ Wk,
                                                   const float* __restrict__ Wv,
                                                   const float* __restrict__ Wo,
                                                   bf16_t* __restrict__ qkvin,
                                                   bf16_t* __restrict__ Wcat,
                                                   bf16_t* __restrict__ Wot,
                                                   int cast_blocks){
  __shared__ float T[32][33];
  int id = blockIdx.x, tid = threadIdx.x;
  if (id < cast_blocks){
    // cast q,k,v fp32 -> bf16 planes (4096 blocks per plane)
    int z = id >> 12;
    int i = (id & 4095) * 256 + tid;
    const float* x = (z == 0) ? q : (z == 1) ? k : v;
    float4 f = reinterpret_cast<const float4*>(x)[i];
    bf16x4v w;
    w[0] = (bf16_t)f.x; w[1] = (bf16_t)f.y; w[2] = (bf16_t)f.z; w[3] = (bf16_t)f.w;
    reinterpret_cast<bf16x4v*>(qkvin + (size_t)z * 4194304)[i] = w;
  } else {
    // weight transpose+cast: 1024 32x32 tiles per weight
    int wid = id - cast_blocks;
    int z = wid >> 10, t = wid & 1023;
    int k0 = (t >> 5) * 32, n0 = (t & 31) * 32;
    int x = tid & 31, y = tid >> 5;  // (32,8) layout
    const float* W = (z == 0) ? Wq : (z == 1) ? Wk : (z == 2) ? Wv : Wo;
    bf16_t* dst = (z < 3) ? (Wcat + (size_t)z * 1024 * 1024) : Wot;
    #pragma unroll
    for (int i = 0; i < 4; i++) T[y + 8*i][x] = W[(size_t)(k0 + y + 8*i) * 1024 + n0 + x];
    __syncthreads();
    #pragma unroll
    for (int i = 0; i < 4; i++) dst[(size_t)(n0 + y + 8*i) * 1024 + k0 + x] = (bf16_t)T[x][y + 8*i];
  }
}

// ---------------- shared epilogue for QKV GEMMs ----------------
// seg 0/1: write q/k planes (scaled). seg 2: write V TRANSPOSED directly into
// Vt[(b*16+h)*64+d][s] (vtrans kernel eliminated). Per (ti,tj): 4 consecutive-s
// values for one fixed column -> one packed 8B store; the 128-contiguous-s span
// per column is filled by the block's threads, so L2 write-combines.
__device__ __forceinline__ void qkv_epilogue(f32x4 (&acc)[4][4], int seg, int n0g, int m0,
                                             int wm, int wn, int l16, int lq,
                                             const float* bias, bf16_t* qp, bf16_t* kp,
                                             bf16_t* Vt){
  if (seg < 2){
    bf16_t* Cp = (seg == 0) ? qp : kp;
    float scale = (seg == 0) ? 0.125f * LOG2E : 1.0f;  // fold softmax scale + log2e into Q
    #pragma unroll
    for (int ti = 0; ti < 4; ti++){
      #pragma unroll
      for (int tj = 0; tj < 4; tj++){
        int col = (n0g + wn + tj*16 + l16) & 1023;
        float bvv = bias[col];
        #pragma unroll
        for (int r = 0; r < 4; r++){
          int row = m0 + wm + ti*16 + lq*4 + r;
          Cp[(size_t)row * 1024 + col] = (bf16_t)((acc[ti][tj][r] + bvv) * scale);
        }
      }
    }
  } else {
    int b = m0 >> 11;                    // rows m0..m0+127 lie in one batch (2048%128==0)
    int s0base = (m0 & 2047) + wm;
    #pragma unroll
    for (int ti = 0; ti < 4; ti++){
      #pragma unroll
      for (int tj = 0; tj < 4; tj++){
        int col = (n0g + wn + tj*16 + l16) & 1023;
        float bvv = bias[col];
        int h = col >> 6, d = col & 63;
        int s0 = s0base + ti*16 + lq*4;
        pk8 w;
        #pragma unroll
        for (int r = 0; r < 4; r++) w.b4[r] = (bf16_t)(acc[ti][tj][r] + bvv);
        *reinterpret_cast<uint2*>(&Vt[((size_t)(b*16 + h)*64 + d) * 2048 + s0]) = w.u2;
      }
    }
  }
}

// ---------------- fused QKV GEMM, all-bf16 (path A): BK=32 dbuf, prefetch-before-compute ----
__global__ __launch_bounds__(256) void gemm_qkv_bf(const bf16_t* __restrict__ qkvin,
                                                   const bf16_t* __restrict__ Wcat,
                                                   const float* __restrict__ bq,
                                                   const float* __restrict__ bk,
                                                   const float* __restrict__ bv,
                                                   bf16_t* __restrict__ qp,
                                                   bf16_t* __restrict__ kp,
                                                   bf16_t* __restrict__ Vt){
  const int K = 1024;
  __shared__ __align__(16) bf16_t As[2][128*32];
  __shared__ __align__(16) bf16_t Bs[2][128*32];
  int tid = threadIdx.x, wave = tid >> 6, lane = tid & 63;
  int l16 = lane & 15, lq = lane >> 4;
  int m0  = blockIdx.x * 128;
  int n0g = blockIdx.y * 128;
  int seg = n0g >> 10;
  const bf16_t* A   = qkvin + (size_t)seg * 4194304;
  const float* bias = (seg == 0) ? bq : (seg == 1) ? bk : bv;
  int wm = (wave >> 1) * 64, wn = (wave & 1) * 64;
  int cposR = lq ^ ((l16 >> 2) & 3);
  f32x4 acc[4][4] = {};

  auto stage = [&](int kt, int bsel){
    #pragma unroll
    for (int i = 0; i < 2; i++){
      int u = tid + 256*i;
      int r = u >> 2, cpos = u & 3, cg = cpos ^ ((r >> 2) & 3);
      int ldsoff = (wave*64 + 256*i) * 16;
      load_lds_16B(&A[(size_t)(m0 + r) * K + kt + cg*8], (char*)As[bsel] + ldsoff);
      load_lds_16B(&Wcat[(size_t)(n0g + r) * K + kt + cg*8], (char*)Bs[bsel] + ldsoff);
    }
  };
  auto compute = [&](int cur){
    bf16x8 af[4], bfr[4];
    #pragma unroll
    for (int t = 0; t < 4; t++) af[t]  = *reinterpret_cast<bf16x8*>(&As[cur][(wm + t*16 + l16)*32 + cposR*8]);
    #pragma unroll
    for (int t = 0; t < 4; t++) bfr[t] = *reinterpret_cast<bf16x8*>(&Bs[cur][(wn + t*16 + l16)*32 + cposR*8]);
    #pragma unroll
    for (int ti = 0; ti < 4; ti++)
      #pragma unroll
      for (int tj = 0; tj < 4; tj++)
        acc[ti][tj] = __builtin_amdgcn_mfma_f32_16x16x32_bf16(af[ti], bfr[tj], acc[ti][tj], 0, 0, 0);
  };

  stage(0, 0);
  __syncthreads();
  #pragma unroll 1
  for (int it = 0; it < 32; ++it){
    if (it < 31) stage((it + 1) * 32, (it + 1) & 1);
    compute(it & 1);
    __syncthreads();
  }
  qkv_epilogue(acc, seg, n0g, m0, wm, wn, l16, lq, bias, qp, kp, Vt);
}

// ---------------- fused QKV GEMM, fp32-A fused-cvt (path B fallback, grid (24,32)) ----------------
__global__ __launch_bounds__(256) void gemm_qkv_f32(const float* __restrict__ qi,
                                                    const float* __restrict__ ki,
                                                    const float* __restrict__ vi,
                                                    const bf16_t* __restrict__ Wcat,
                                                    const float* __restrict__ bq,
                                                    const float* __restrict__ bk,
                                                    const float* __restrict__ bv,
                                                    bf16_t* __restrict__ qp,
                                                    bf16_t* __restrict__ kp,
                                                    bf16_t* __restrict__ Vt){
  const int K = 1024;
  __shared__ __align__(16) float  Asf[128*32];
  __shared__ __align__(16) bf16_t Bs[128*32];
  int tid = threadIdx.x, wave = tid >> 6, lane = tid & 63;
  int l16 = lane & 15, lq = lane >> 4;
  int n0g = blockIdx.x * 128;
  int seg = n0g >> 10;
  const float* A    = (seg == 0) ? qi : (seg == 1) ? ki : vi;
  const float* bias = (seg == 0) ? bq : (seg == 1) ? bk : bv;
  int m0 = blockIdx.y * 128;
  int wm = (wave >> 1) * 64, wn = (wave & 1) * 64;
  int cposR = lq ^ ((l16 >> 2) & 3);
  int ca0 = (2*lq)     ^ (l16 & 7);
  int ca1 = (2*lq + 1) ^ (l16 & 7);
  f32x4 acc[4][4] = {};
  for (int kt = 0; kt < K; kt += 32){
    __syncthreads();
    #pragma unroll
    for (int i = 0; i < 4; i++){
      int u = tid + 256*i;
      int r = u >> 3, cpos = u & 7, cg = cpos ^ (r & 7);
      load_lds_16B(&A[(size_t)(m0 + r) * K + kt + cg*4], (char*)Asf + (wave*64 + 256*i)*16);
    }
    #pragma unroll
    for (int i = 0; i < 2; i++){
      int u = tid + 256*i;
      int r = u >> 2, cpos = u & 3, cg = cpos ^ ((r >> 2) & 3);
      load_lds_16B(&Wcat[(size_t)(n0g + r) * K + kt + cg*8], (char*)Bs + (wave*64 + 256*i)*16);
    }
    __syncthreads();
    bf16x8 af[4], bfr[4];
    #pragma unroll
    for (int t = 0; t < 4; t++){
      int row = wm + t*16 + l16;
      f32x4 x0 = *reinterpret_cast<f32x4*>(&Asf[row*32 + ca0*4]);
      f32x4 x1 = *reinterpret_cast<f32x4*>(&Asf[row*32 + ca1*4]);
      bf16x8 a;
      a[0] = (bf16_t)x0[0]; a[1] = (bf16_t)x0[1]; a[2] = (bf16_t)x0[2]; a[3] = (bf16_t)x0[3];
      a[4] = (bf16_t)x1[0]; a[5] = (bf16_t)x1[1]; a[6] = (bf16_t)x1[2]; a[7] = (bf16_t)x1[3];
      af[t] = a;
    }
    #pragma unroll
    for (int t = 0; t < 4; t++) bfr[t] = *reinterpret_cast<bf16x8*>(&Bs[(wn + t*16 + l16)*32 + cposR*8]);
    #pragma unroll
    for (int ti = 0; ti < 4; ti++)
      #pragma unroll
      for (int tj = 0; tj < 4; tj++)
        acc[ti][tj] = __builtin_amdgcn_mfma_f32_16x16x32_bf16(af[ti], bfr[tj], acc[ti][tj], 0, 0, 0);
  }
  qkv_epilogue(acc, seg, n0g, m0, wm, wn, l16, lq, bias, qp, kp, Vt);
}

// ---------------- output GEMM: BK=64 dbuf prefetch; grid (32 m, 16 n) ----------------
__global__ __launch_bounds__(256) void gemm_out(const bf16_t* __restrict__ A,
                                                const bf16_t* __restrict__ Bt,
                                                const float* __restrict__ bias,
                                                float* __restrict__ C){
  const int K = 1024, N = 1024;
  __shared__ __align__(16) bf16_t As[2][128*64];
  __shared__ __align__(16) bf16_t Bs[2][64*64];
  int tid = threadIdx.x, wave = tid >> 6, lane = tid & 63;
  int l16 = lane & 15, lq = lane >> 4;
  int m0 = blockIdx.x * 128, n0 = blockIdx.y * 64;
  int wm = wave * 32;
  f32x4 acc[2][4] = {};

  auto stage = [&](int kt, int bsel){
    #pragma unroll
    for (int i = 0; i < 4; i++){
      int u = tid + 256*i;
      int r = u >> 3, cpos = u & 7, cg = cpos ^ (r & 7);
      load_lds_16B(&A[(size_t)(m0 + r) * K + kt + cg*8], (char*)As[bsel] + (wave*64 + 256*i)*16);
    }
    #pragma unroll
    for (int i = 0; i < 2; i++){
      int u = tid + 256*i;
      int r = u >> 3, cpos = u & 7, cg = cpos ^ (r & 7);
      load_lds_16B(&Bt[(size_t)(n0 + r) * K + kt + cg*8], (char*)Bs[bsel] + (wave*64 + 256*i)*16);
    }
  };
  auto compute = [&](int cur){
    #pragma unroll
    for (int kk = 0; kk < 2; kk++){
      bf16x8 af[2], bfr[4];
      #pragma unroll
      for (int t = 0; t < 2; t++){
        int row = wm + t*16 + l16, cpos = (kk*4 + lq) ^ (l16 & 7);
        af[t] = *reinterpret_cast<bf16x8*>(&As[cur][row*64 + cpos*8]);
      }
      #pragma unroll
      for (int t = 0; t < 4; t++){
        int row = t*16 + l16, cpos = (kk*4 + lq) ^ (l16 & 7);
        bfr[t] = *reinterpret_cast<bf16x8*>(&Bs[cur][row*64 + cpos*8]);
      }
      #pragma unroll
      for (int ti = 0; ti < 2; ti++)
        #pragma unroll
        for (int tj = 0; tj < 4; tj++)
          acc[ti][tj] = __builtin_amdgcn_mfma_f32_16x16x32_bf16(af[ti], bfr[tj], acc[ti][tj], 0, 0, 0);
    }
  };

  stage(0, 0);
  __syncthreads();
  #pragma unroll 1
  for (int it = 0; it < 16; ++it){
    if (it < 15) stage((it + 1) * 64, (it + 1) & 1);
    compute(it & 1);
    __syncthreads();
  }

  #pragma unroll
  for (int ti = 0; ti < 2; ti++){
    #pragma unroll
    for (int tj = 0; tj < 4; tj++){
      int col = n0 + tj*16 + l16;
      float bvv = bias[col];
      #pragma unroll
      for (int r = 0; r < 4; r++){
        int row = m0 + wm + ti*16 + lq*4 + r;
        C[(size_t)row * N + col] = acc[ti][tj][r] + bvv;
      }
    }
  }
}

// ---------------- flash attention v10 (unchanged from R7) ----------------
__global__ __launch_bounds__(512, 4) void attn_kernel(const bf16_t* __restrict__ qp,
                                                      const bf16_t* __restrict__ kp,
                                                      const bf16_t* __restrict__ vt,
                                                      const float* __restrict__ mask,
                                                      bf16_t* __restrict__ ctx){
  const int S = 2048, D = 1024, HD = 64;
  __shared__ __align__(16) char smem[74240];
  float* Lsum  = (float*)(smem + 73728);   // [128]
  float* Opart = (float*)smem;             // epilogue overlay: 32 KB
  float* Mlw   = (float*)(smem + 65536);   // mask f32 [2048]
  const float* Ml = Mlw;
  int tid = threadIdx.x, wave = tid >> 6, lane = tid & 63;
  int l32 = lane & 31, H = lane >> 5;
  int qo = wave >> 1, khalf = wave & 1;
  int h = blockIdx.x, b = blockIdx.y, qt = blockIdx.z;
  const bf16_t* Qg = qp + (size_t)b*S*D + h*HD;
  const bf16_t* Kg = kp + (size_t)b*S*D + h*HD;
  const bf16_t* Vg = vt + (size_t)(b*16 + h)*HD*S;
  const float*  Mg = mask + (size_t)b*S;

  auto stage = [&](int kt, int bsel){
    char* Kd = smem + bsel*8192;
    char* Vd = smem + 32768 + bsel*8192;
    int r = tid >> 3, c = tid & 7, cg = c ^ (r & 7);
    int ldsoff = wave * 1024;  // wave-uniform base; HW adds lane*16
    load_lds_16B(&Kg[(size_t)(kt + r) * D + cg*8], Kd + ldsoff);
    load_lds_16B(&Vg[(size_t)r * S + kt + cg*8], Vd + ldsoff);
  };

  int qrow = qt*128 + qo*32 + l32;
  bf16x8 qf[4];
  #pragma unroll
  for (int s = 0; s < 4; s++)
    qf[s] = *reinterpret_cast<const bf16x8*>(&Qg[(size_t)qrow * D + s*16 + 8*H]);

  f32x16 o0 = zero16(), o1 = zero16(), lmm = zero16();
  int krow = khalf*32 + l32;

  pk16 ones;
  ones.h[0].x = 0x3F803F80u; ones.h[0].y = 0x3F803F80u;
  ones.h[1].x = 0x3F803F80u; ones.h[1].y = 0x3F803F80u;

  // prologue: raw mask row (8 KB) + tiles 0,1; then scale mask in LDS
  load_lds_16B(&Mg[(size_t)tid*4], smem + 65536 + wave*1024);
  stage(0, 0);
  stage(64, 1);
  __syncthreads();
  {
    f32x4 mv = *reinterpret_cast<f32x4*>(&Mlw[tid*4]);
    mv *= MBIAS_C;
    *reinterpret_cast<f32x4*>(&Mlw[tid*4]) = mv;
  }
  __syncthreads();

  auto tile_compute = [&](int kt, int cur){
    bf16_t* Ks  = (bf16_t*)(smem + cur*8192);
    bf16_t* Vts = (bf16_t*)(smem + 32768 + cur*8192);
    cinit_t ci;
    #pragma unroll
    for (int g = 0; g < 4; g++)
      ci.f4[g] = *reinterpret_cast<const float4*>(&Ml[kt + khalf*32 + 8*g + 4*H]);
    f32x16 sc;
    __builtin_amdgcn_s_setprio(1);
    #pragma unroll
    for (int s = 0; s < 4; s++){
      int cp = (2*s + H) ^ (l32 & 7);  // krow&7 == l32&7
      bf16x8 kf = *reinterpret_cast<bf16x8*>(&Ks[krow*64 + cp*8]);
      if (s == 0) sc = __builtin_amdgcn_mfma_f32_32x32x16_bf16(kf, qf[0], ci.v, 0, 0, 0);
      else        sc = __builtin_amdgcn_mfma_f32_32x32x16_bf16(kf, qf[s], sc, 0, 0, 0);
    }
    __builtin_amdgcn_s_setprio(0);
    pk8 grp[4];
    #pragma unroll
    for (int g = 0; g < 4; g++){
      float p0 = EXP2F(sc[4*g+0]);
      float p1 = EXP2F(sc[4*g+1]);
      float p2 = EXP2F(sc[4*g+2]);
      float p3 = EXP2F(sc[4*g+3]);
      pk8 w;
      w.b4[0] = (bf16_t)p0; w.b4[1] = (bf16_t)p1; w.b4[2] = (bf16_t)p2; w.b4[3] = (bf16_t)p3;
      grp[g] = w;
    }
    #pragma unroll
    for (int kk = 0; kk < 2; kk++){
      uint2 ga = grp[2*kk].u2;
      uint2 gb = grp[2*kk+1].u2;
      uint2 send = H ? ga : gb;
      uint2 recv;
      recv.x = (unsigned)__shfl_xor((int)send.x, 32);
      recv.y = (unsigned)__shfl_xor((int)send.y, 32);
      pk16 fr;
      fr.h[0] = H ? recv : ga;
      fr.h[1] = H ? gb : recv;
      int cp = (4*khalf + 2*kk + H) ^ (l32 & 7);
      bf16x8 vf0 = *reinterpret_cast<bf16x8*>(&Vts[l32*64 + cp*8]);
      bf16x8 vf1 = *reinterpret_cast<bf16x8*>(&Vts[(32 + l32)*64 + cp*8]);
      __builtin_amdgcn_s_setprio(1);
      o0  = __builtin_amdgcn_mfma_f32_32x32x16_bf16(fr.b8, vf0, o0, 0, 0, 0);
      o1  = __builtin_amdgcn_mfma_f32_32x32x16_bf16(fr.b8, vf1, o1, 0, 0, 0);
      lmm = __builtin_amdgcn_mfma_f32_32x32x16_bf16(fr.b8, ones.b8, lmm, 0, 0, 0);
      __builtin_amdgcn_s_setprio(0);
    }
  };

  #pragma unroll 2
  for (int it = 0; it < 16; ++it){
    int kt = it * 128;
    if (it < 15){
      stage(kt + 128, (2*it + 2) & 3);
      stage(kt + 192, (2*it + 3) & 3);
    }
    tile_compute(kt,      (2*it) & 3);
    tile_compute(kt + 64, (2*it + 1) & 3);
    __syncthreads();
  }

  if (khalf == 1){
    #pragma unroll
    for (int reg = 0; reg < 16; reg++){
      Opart[qo*2048 + reg*64 + lane]        = o0[reg];
      Opart[qo*2048 + 1024 + reg*64 + lane] = o1[reg];
    }
    if (l32 == 0){
      #pragma unroll
      for (int reg = 0; reg < 16; reg++)
        Lsum[qo*32 + (reg & 3) + 8*(reg >> 2) + 4*H] = lmm[reg];
    }
  }
  __syncthreads();
  if (khalf == 0){
    #pragma unroll
    for (int reg = 0; reg < 16; reg++){
      o0[reg] += Opart[qo*2048 + reg*64 + lane];
      o1[reg] += Opart[qo*2048 + 1024 + reg*64 + lane];
    }
    #pragma unroll
    for (int g = 0; g < 4; g++){
      #pragma unroll
      for (int r = 0; r < 4; r++){
        float lf = lmm[4*g + r] + Lsum[qo*32 + 8*g + 4*H + r];
        float inv = 1.f / lf;
        int grow = qt*128 + qo*32 + 8*g + 4*H + r;
        size_t base = (size_t)(b*S + grow) * D + h*HD;
        ctx[base + l32]      = (bf16_t)(o0[4*g + r] * inv);
        ctx[base + 32 + l32] = (bf16_t)(o1[4*g + r] * inv);
      }
    }
  }
}

extern "C" void kernel_launch(void* const* d_in, const int* in_sizes, int n_in,
                              void* d_out, int out_size, void* d_ws, size_t ws_size,
                              hipStream_t stream){
  const float* q    = (const float*)d_in[0];
  const float* k    = (const float*)d_in[1];
  const float* v    = (const float*)d_in[2];
  const float* mask = (const float*)d_in[3];
  const float* Wq   = (const float*)d_in[4];
  const float* bq   = (const float*)d_in[5];
  const float* Wk   = (const float*)d_in[6];
  const float* bk   = (const float*)d_in[7];
  const float* Wv   = (const float*)d_in[8];
  const float* bv   = (const float*)d_in[9];
  const float* Wo   = (const float*)d_in[10];
  const float* bo   = (const float*)d_in[11];

  char* ws = (char*)d_ws;
  bf16_t* qp    = (bf16_t*)(ws);               // [0, 8 MiB)
  bf16_t* kp    = (bf16_t*)(ws + 8388608);     // [8, 16)
  bf16_t* Vt    = (bf16_t*)(ws + 16777216);    // [16, 24) (old vh slot; written by gemm_qkv)
  bf16_t* Wcat  = (bf16_t*)(ws + 25165824);    // [24, 30)
  bf16_t* Wot   = (bf16_t*)(ws + 31457280);    // [30, 32)
  bf16_t* ctx   = (bf16_t*)(ws + 41943040);    // [40, 48) overlays qkvin k-plane (dead after gemm_qkv)
  bf16_t* qkvin = (bf16_t*)(ws + 33554432);    // [32, 56) path A only

  if (ws_size >= 58720256){
    prep_kernel<<<dim3(16384), 256, 0, stream>>>(q, k, v, Wq, Wk, Wv, Wo, qkvin, Wcat, Wot, 12288);
    gemm_qkv_bf<<<dim3(32,24), 256, 0, stream>>>(qkvin, Wcat, bq, bk, bv, qp, kp, Vt);
  } else {
    prep_kernel<<<dim3(4096), 256, 0, stream>>>(q, k, v, Wq, Wk, Wv, Wo, qkvin, Wcat, Wot, 0);
    gemm_qkv_f32<<<dim3(24,32), 256, 0, stream>>>(q, k, v, Wcat, bq, bk, bv, qp, kp, Vt);
  }
  attn_kernel<<<dim3(16,2,16), 512, 0, stream>>>(qp, kp, Vt, mask, ctx);
  gemm_out<<<dim3(32,16), 256, 0, stream>>>(ctx, Wot, bo, (float*)d_out);
}